// Round 5
// baseline (247.146 us; speedup 1.0000x reference)
//
#include <hip/hip_runtime.h>

typedef __bf16 bf16;
typedef __bf16 bf16x4 __attribute__((ext_vector_type(4)));
typedef __bf16 bf16x8 __attribute__((ext_vector_type(8)));
typedef float f32x4 __attribute__((ext_vector_type(4)));

#define MFMA16(a, b, c) __builtin_amdgcn_mfma_f32_16x16x32_bf16((a), (b), (c), 0, 0, 0)

__device__ __forceinline__ int swz16(int r, int c) { return (c ^ (r & 15)); }
__device__ __forceinline__ int swz8(int r, int c) { return (c ^ (r & 7)); }

// ---- fused weight transposes: z=0..2 Wq/Wk/Wv (128x1024), z=3 Wo (1024x128) ----
__global__ __launch_bounds__(256) void trW_kernel(
    const float* __restrict__ Wq, const float* __restrict__ Wk,
    const float* __restrict__ Wv, const float* __restrict__ Wo,
    bf16* __restrict__ outbase) {
  __shared__ bf16 tile[32][33];
  const int z = blockIdx.z;
  const float* ib = (z == 0) ? Wq : (z == 1) ? Wk : (z == 2) ? Wv : Wo;
  bf16* ob = outbase + (size_t)z * 131072;
  const int R = (z < 3) ? 128 : 1024;   // input rows
  const int C = (z < 3) ? 1024 : 128;   // input cols
  int r0 = (z < 3) ? blockIdx.y * 32 : blockIdx.x * 32;
  int c0 = (z < 3) ? blockIdx.x * 32 : blockIdx.y * 32;
  int tx = threadIdx.x & 31, ty = threadIdx.x >> 5;
#pragma unroll
  for (int i = 0; i < 4; ++i) {
    int r = ty + i * 8;
    tile[r][tx] = (bf16)ib[(size_t)(r0 + r) * C + (c0 + tx)];
  }
  __syncthreads();
#pragma unroll
  for (int i = 0; i < 4; ++i) {
    int r = ty + i * 8;
    ob[(size_t)(c0 + r) * R + (r0 + tx)] = tile[tx][r];
  }
}

// -------- QKV projection: fp32 x [4096x128] @ Wt -> Q/K [bh][t][d], V [bh][d][t] ----
__global__ __launch_bounds__(256) void proj_gemm(
    const float* __restrict__ x, const bf16* __restrict__ Wqt,
    const bf16* __restrict__ Wkt, const bf16* __restrict__ Wvt,
    bf16* __restrict__ Qb, bf16* __restrict__ Kb, bf16* __restrict__ Vt) {
  __shared__ __align__(16) bf16 As[128 * 128];
  __shared__ __align__(16) bf16 Bs[128 * 128];
  const int mt = blockIdx.x;  // 32 tiles of 128 token-rows
  const int nt = blockIdx.y;  // 24 tiles of 128 cols (8 per matrix)
  const int matid = nt >> 3, h = nt & 7;
  const bf16* W = (matid == 0) ? Wqt : (matid == 1) ? Wkt : Wvt;
  const int tid = threadIdx.x;
  const bf16* sb = W + (size_t)h * 128 * 128;
#pragma unroll
  for (int i = 0; i < 8; ++i) {  // stage x tile, fp32 -> bf16
    int c = tid + i * 256;
    int r = c >> 4, cc = c & 15;
    const f32x4* p = (const f32x4*)(x + (size_t)(mt * 128 + r) * 128 + cc * 8);
    f32x4 a = p[0], b = p[1];
    bf16x8 o;
#pragma unroll
    for (int j = 0; j < 4; ++j) { o[j] = (bf16)a[j]; o[4 + j] = (bf16)b[j]; }
    *(bf16x8*)&As[r * 128 + swz16(r, cc) * 8] = o;
  }
#pragma unroll
  for (int i = 0; i < 8; ++i) {
    int c = tid + i * 256;
    int r = c >> 4, cc = c & 15;
    *(bf16x8*)&Bs[r * 128 + swz16(r, cc) * 8] = *(const bf16x8*)(sb + (size_t)r * 128 + cc * 8);
  }
  __syncthreads();
  const int wave = tid >> 6, lane = tid & 63;
  const int wr = (wave >> 1) * 64, wc = (wave & 1) * 64;
  const int lr = lane & 15, lkb = lane >> 4;
  const f32x4 FZ = {0.f, 0.f, 0.f, 0.f};
  f32x4 acc[4][4];
#pragma unroll
  for (int mf = 0; mf < 4; ++mf)
#pragma unroll
    for (int nf = 0; nf < 4; ++nf) acc[mf][nf] = FZ;
  const bool qk = (matid < 2);
#pragma unroll
  for (int ks = 0; ks < 4; ++ks) {
    bf16x8 a[4], b[4];
#pragma unroll
    for (int mf = 0; mf < 4; ++mf) {
      int r = wr + mf * 16 + lr;
      a[mf] = *(const bf16x8*)&As[r * 128 + swz16(r, ks * 4 + lkb) * 8];
    }
#pragma unroll
    for (int nf = 0; nf < 4; ++nf) {
      int r = wc + nf * 16 + lr;
      b[nf] = *(const bf16x8*)&Bs[r * 128 + swz16(r, ks * 4 + lkb) * 8];
    }
    if (qk) {  // transposed output: C[row=n][col=m] -> vectorizable d-runs
#pragma unroll
      for (int mf = 0; mf < 4; ++mf)
#pragma unroll
        for (int nf = 0; nf < 4; ++nf) acc[mf][nf] = MFMA16(b[nf], a[mf], acc[mf][nf]);
    } else {
#pragma unroll
      for (int mf = 0; mf < 4; ++mf)
#pragma unroll
        for (int nf = 0; nf < 4; ++nf) acc[mf][nf] = MFMA16(a[mf], b[nf], acc[mf][nf]);
    }
  }
  const int rb = lkb * 4;
  if (qk) {  // Q/K: [bh][t][d]; lane holds 4 consecutive d for one token
    bf16* Out = (matid == 0) ? Qb : Kb;
#pragma unroll
    for (int mf = 0; mf < 4; ++mf)
#pragma unroll
      for (int nf = 0; nf < 4; ++nf) {
        int m = mt * 128 + wr + mf * 16 + lr;  // token
        int d0 = wc + nf * 16 + rb;            // 4 consecutive dims
        int bb = m >> 11, t = m & 2047;
        bf16x4 vv;
#pragma unroll
        for (int r = 0; r < 4; ++r) vv[r] = (bf16)acc[mf][nf][r];
        *(bf16x4*)(Out + ((size_t)(bb * 8 + h) * 2048 + t) * 128 + d0) = vv;
      }
  } else {  // V: [bh][d][t]; lane holds 4 consecutive tokens for one dim
#pragma unroll
    for (int mf = 0; mf < 4; ++mf)
#pragma unroll
      for (int nf = 0; nf < 4; ++nf) {
        int d = wc + nf * 16 + lr;
        int m0 = mt * 128 + wr + mf * 16 + rb;
        int bb = m0 >> 11, t0 = m0 & 2047;
        bf16x4 vv;
#pragma unroll
        for (int r = 0; r < 4; ++r) vv[r] = (bf16)acc[mf][nf][r];
        *(bf16x4*)(Vt + ((size_t)(bb * 8 + h) * 128 + d) * 2048 + t0) = vv;
      }
  }
}

// ---- causal flash attention: 512 blocks x 512 thr; in-block kv-split (2 groups) ----
// group g of waves handles kv tiles [g? h0:0, g? nT:h0); merged at the end via LDS.
__global__ __launch_bounds__(512, 4) void attn_kernel(
    bf16* __restrict__ Qb, const bf16* __restrict__ Kb, const bf16* __restrict__ Vt) {
  extern __shared__ char smem[];  // 81920 B
  const f32x4 FZ = {0.f, 0.f, 0.f, 0.f};
  const int bid = blockIdx.x;
  const int qt = 31 - (bid >> 4);
  const int bh = bid & 15;
  const int nT = qt + 1;
  const int h0 = (nT + 1) >> 1, h1 = nT - h0;
  const bf16* Qh = Qb + (size_t)bh * 2048 * 128;
  bf16* Qw = Qb + (size_t)bh * 2048 * 128;
  const bf16* Kh = Kb + (size_t)bh * 2048 * 128;
  const bf16* Vh = Vt + (size_t)bh * 128 * 2048;
  const int tid = threadIdx.x, wave = tid >> 6, lane = tid & 63;
  const int g = tid >> 8;            // wave-group 0/1
  const int tg = tid & 255;          // tid within group
  const int gw = wave & 3;           // wave within group
  const int lr = lane & 15, lkb = lane >> 4, rb = lkb * 4;
  const float SCL = 0.12751744f;     // log2(e)/sqrt(128)
  const int qrow = qt * 64 + gw * 16;
  const int hg = g ? h1 : h0;        // this group's tile count
  const int tbase = g ? h0 : 0;      // this group's first kv tile

  bf16* Ks = (bf16*)(smem + g * 16384);
  bf16* Vs = (bf16*)(smem + 32768 + g * 16384);
  bf16* Ps = (bf16*)(smem + 65536) + wave * 1024;

  // loop-invariant staging addresses (per group: 256 threads stage 64x128 K, 128x64 V)
  const int krow = tg >> 4, kcc = tg & 15;
  bf16* kdst = &Ks[krow * 128 + (kcc ^ krow) * 8];
  const bf16* ksrc0 = Kh + (size_t)krow * 128 + kcc * 8;
  const int vrow = tg >> 3, vcc = tg & 7;
  bf16* vdst = &Vs[vrow * 64 + (vcc ^ (vrow & 7)) * 8];
  const bf16* vsrc0 = Vh + (size_t)vrow * 2048 + vcc * 8;

  float mrun[4], lrun[4];
  f32x4 O[8];
  bf16x8 qf[4];
#pragma unroll
  for (int r = 0; r < 4; ++r) { mrun[r] = -__builtin_inff(); lrun[r] = 0.f; }
#pragma unroll
  for (int nf = 0; nf < 8; ++nf) O[nf] = FZ;
#pragma unroll
  for (int ks = 0; ks < 4; ++ks)
    qf[ks] = *(const bf16x8*)(Qh + (size_t)(qrow + lr) * 128 + ks * 32 + lkb * 8);

  bf16x8 kpre[4], vpre[4];
  if (hg > 0) {  // prefetch this group's first tile
    const size_t ko = (size_t)tbase * 8192, vo = (size_t)tbase * 64;
#pragma unroll
    for (int i = 0; i < 4; ++i) kpre[i] = *(const bf16x8*)(ksrc0 + ko + i * 2048);
#pragma unroll
    for (int i = 0; i < 4; ++i) vpre[i] = *(const bf16x8*)(vsrc0 + vo + i * 65536);
  }

  for (int it = 0; it < h0; ++it) {
    const bool act = (it < hg);
    const int kvt = tbase + it;
    __syncthreads();  // previous iteration's LDS reads complete
    if (act) {
#pragma unroll
      for (int i = 0; i < 4; ++i) *(bf16x8*)(kdst + i * 2048) = kpre[i];
#pragma unroll
      for (int i = 0; i < 4; ++i) *(bf16x8*)(vdst + i * 2048) = vpre[i];
    }
    __syncthreads();  // staged tiles visible
    if (it + 1 < hg) {  // issue next tile's loads; land during compute
      const size_t ko = (size_t)(kvt + 1) * 8192, vo = (size_t)(kvt + 1) * 64;
#pragma unroll
      for (int i = 0; i < 4; ++i) kpre[i] = *(const bf16x8*)(ksrc0 + ko + i * 2048);
#pragma unroll
      for (int i = 0; i < 4; ++i) vpre[i] = *(const bf16x8*)(vsrc0 + vo + i * 65536);
    }
    if (!act) continue;
    // S = Q K^T (raw, unscaled)
    f32x4 s[4];
#pragma unroll
    for (int nf = 0; nf < 4; ++nf) s[nf] = FZ;
#pragma unroll
    for (int ks = 0; ks < 4; ++ks) {
#pragma unroll
      for (int nf = 0; nf < 4; ++nf) {
        int r = nf * 16 + lr;
        bf16x8 b = *(const bf16x8*)&Ks[r * 128 + swz16(r, ks * 4 + lkb) * 8];
        s[nf] = MFMA16(qf[ks], b, s[nf]);
      }
    }
    // raw-domain max (mask only on the diagonal tile; uniform branch)
    float pmax[4];
#pragma unroll
    for (int r = 0; r < 4; ++r) pmax[r] = -__builtin_inff();
    if (kvt == qt) {
#pragma unroll
      for (int nf = 0; nf < 4; ++nf) {
        int colg = (qt << 6) + nf * 16 + lr;
#pragma unroll
        for (int r = 0; r < 4; ++r) {
          int rowg = qrow + rb + r;
          float v = (colg > rowg) ? -__builtin_inff() : s[nf][r];
          s[nf][r] = v;
          pmax[r] = fmaxf(pmax[r], v);
        }
      }
    } else {
#pragma unroll
      for (int nf = 0; nf < 4; ++nf)
#pragma unroll
        for (int r = 0; r < 4; ++r) pmax[r] = fmaxf(pmax[r], s[nf][r]);
    }
#pragma unroll
    for (int r = 0; r < 4; ++r) {  // reduce across the 16 lanes sharing these rows
      float v = pmax[r];
      v = fmaxf(v, __shfl_xor(v, 1, 64));
      v = fmaxf(v, __shfl_xor(v, 2, 64));
      v = fmaxf(v, __shfl_xor(v, 4, 64));
      v = fmaxf(v, __shfl_xor(v, 8, 64));
      pmax[r] = v;
    }
    float alpha[4];
#pragma unroll
    for (int r = 0; r < 4; ++r) {
      float mnew = fmaxf(mrun[r], pmax[r] * SCL);
      alpha[r] = exp2f(mrun[r] - mnew);
      mrun[r] = mnew;
    }
    float psum[4] = {0.f, 0.f, 0.f, 0.f};
#pragma unroll
    for (int nf = 0; nf < 4; ++nf)
#pragma unroll
      for (int r = 0; r < 4; ++r) {
        float p = exp2f(__builtin_fmaf(s[nf][r], SCL, -mrun[r]));
        s[nf][r] = p;
        psum[r] += p;
      }
#pragma unroll
    for (int r = 0; r < 4; ++r) {
      float v = psum[r];
      v += __shfl_xor(v, 1, 64);
      v += __shfl_xor(v, 2, 64);
      v += __shfl_xor(v, 4, 64);
      v += __shfl_xor(v, 8, 64);
      lrun[r] = lrun[r] * alpha[r] + v;
    }
#pragma unroll
    for (int nf = 0; nf < 8; ++nf) {
#pragma unroll
      for (int r = 0; r < 4; ++r) O[nf][r] *= alpha[r];
    }
    // P -> per-wave LDS (re-fragment for PV A-operand); wave-private, no barrier
#pragma unroll
    for (int nf = 0; nf < 4; ++nf) {
#pragma unroll
      for (int r = 0; r < 4; ++r) {
        int row = rb + r;
        int col = nf * 16 + lr;
        Ps[row * 64 + swz8(row, col >> 3) * 8 + (col & 7)] = (bf16)s[nf][r];
      }
    }
    // O += P @ V
#pragma unroll
    for (int ks2 = 0; ks2 < 2; ++ks2) {
      bf16x8 a = *(const bf16x8*)&Ps[lr * 64 + swz8(lr, ks2 * 4 + lkb) * 8];
#pragma unroll
      for (int nf = 0; nf < 8; ++nf) {
        int r = nf * 16 + lr;
        bf16x8 b = *(const bf16x8*)&Vs[r * 64 + swz8(r, ks2 * 4 + lkb) * 8];
        O[nf] = MFMA16(a, b, O[nf]);
      }
    }
  }

  // ---- merge the two groups' (m, l, O) via LDS, then write over Q rows ----
  float* Om = (float*)smem;            // [64][128]
  float* Lm = (float*)(smem + 32768);  // [64]
  float* Ll = (float*)(smem + 33280);  // [64]
  __syncthreads();  // all compute (LDS reads) done
  if (g == 1) {
#pragma unroll
    for (int nf = 0; nf < 8; ++nf)
#pragma unroll
      for (int r = 0; r < 4; ++r)
        Om[(gw * 16 + rb + r) * 128 + nf * 16 + lr] = O[nf][r];
    if (lr == 0) {
#pragma unroll
      for (int r = 0; r < 4; ++r) {
        Lm[gw * 16 + rb + r] = mrun[r];
        Ll[gw * 16 + rb + r] = lrun[r];
      }
    }
  }
  __syncthreads();
  if (g == 0) {
#pragma unroll
    for (int r = 0; r < 4; ++r) {
      int row = gw * 16 + rb + r;
      float m1 = Lm[row], l1 = Ll[row];
      float m = fmaxf(mrun[r], m1);
      float a0 = exp2f(mrun[r] - m), a1 = exp2f(m1 - m);
      float inv = 1.f / (lrun[r] * a0 + l1 * a1);
      int t = qrow + rb + r;
#pragma unroll
      for (int nf = 0; nf < 8; ++nf) {
        float o1 = Om[row * 128 + nf * 16 + lr];
        Qw[(size_t)t * 128 + nf * 16 + lr] =
            (bf16)((O[nf][r] * a0 + o1 * a1) * inv);
      }
    }
  }
}

// ------- output projection: AO [bh][t][128] @ Wot [128][1024] + bo -> fp32 out ------
__global__ __launch_bounds__(256) void outproj_kernel(
    const bf16* __restrict__ AO, const bf16* __restrict__ Wot,
    const float* __restrict__ bo, float* __restrict__ out) {
  __shared__ __align__(16) bf16 As[32 * 128];
  __shared__ __align__(16) bf16 Bs[128 * 128];
  const f32x4 FZ = {0.f, 0.f, 0.f, 0.f};
  const int mt = blockIdx.x;  // 128 tiles of 32 rows
  const int tid = threadIdx.x, wave = tid >> 6, lane = tid & 63;
  const int lr = lane & 15, lkb = lane >> 4, rb = lkb * 4;
  const int wr = (wave >> 1) * 16, wc = (wave & 1) * 64;
  f32x4 acc[4];
#pragma unroll
  for (int nf = 0; nf < 4; ++nf) acc[nf] = FZ;
  for (int kt = 0; kt < 8; ++kt) {  // kt == head index (k-chunk of 128)
    __syncthreads();
#pragma unroll
    for (int i = 0; i < 2; ++i) {
      int c = tid + i * 256;
      int r = c >> 4, cc = c & 15;
      int m = mt * 32 + r, bb = m >> 11, t = m & 2047;
      *(bf16x8*)&As[r * 128 + swz16(r, cc) * 8] =
          *(const bf16x8*)(AO + ((size_t)(bb * 8 + kt) * 2048 + t) * 128 + cc * 8);
    }
#pragma unroll
    for (int i = 0; i < 8; ++i) {
      int c = tid + i * 256;
      int r = c >> 4, cc = c & 15;
      *(bf16x8*)&Bs[r * 128 + swz16(r, cc) * 8] =
          *(const bf16x8*)(Wot + (size_t)r * 1024 + kt * 128 + cc * 8);
    }
    __syncthreads();
#pragma unroll
    for (int ks = 0; ks < 4; ++ks) {
      int ra = wr + lr;
      bf16x8 a = *(const bf16x8*)&As[ra * 128 + swz16(ra, ks * 4 + lkb) * 8];
#pragma unroll
      for (int nf = 0; nf < 4; ++nf) {
        int r = wc + nf * 16 + lr;
        bf16x8 b = *(const bf16x8*)&Bs[r * 128 + swz16(r, ks * 4 + lkb) * 8];
        acc[nf] = MFMA16(a, b, acc[nf]);
      }
    }
  }
#pragma unroll
  for (int nf = 0; nf < 4; ++nf)
#pragma unroll
    for (int r = 0; r < 4; ++r) {
      int m = mt * 32 + wr + rb + r;
      int n = wc + nf * 16 + lr;
      out[(size_t)m * 128 + n] = acc[nf][r] + bo[n];
    }
}

extern "C" void kernel_launch(void* const* d_in, const int* in_sizes, int n_in,
                              void* d_out, int out_size, void* d_ws, size_t ws_size,
                              hipStream_t stream) {
  (void)in_sizes; (void)n_in; (void)out_size; (void)ws_size;
  const float* x  = (const float*)d_in[0];   // [4096][128] fp32
  const float* Wq = (const float*)d_in[1];   // [128][1024] fp32
  const float* Wk = (const float*)d_in[2];
  const float* Wv = (const float*)d_in[3];
  const float* Wo = (const float*)d_in[4];   // [1024][128] fp32
  const float* bo = (const float*)d_in[5];   // [128] fp32
  float* out = (float*)d_out;                // [4096][128] fp32

  // ws layout (bf16 elements): total 13,107,200 el = 25 MB
  bf16* ws  = (bf16*)d_ws;
  bf16* Wqt = ws;                 // [3][1024][128] (q,k,v transposed weights)
  bf16* Wkt = Wqt + 131072;
  bf16* Wvt = Wkt + 131072;
  bf16* Wot = Wvt + 131072;       // [128][1024]
  bf16* Qb  = Wot + 131072;       // [16][2048][128]; attn output written in-place
  bf16* Kb  = Qb + 4194304;       // [16][2048][128]
  bf16* Vt  = Kb + 4194304;       // [16][128][2048]

  trW_kernel<<<dim3(32, 4, 4), 256, 0, stream>>>(Wq, Wk, Wv, Wo, Wqt);
  proj_gemm<<<dim3(32, 24, 1), 256, 0, stream>>>(x, Wqt, Wkt, Wvt, Qb, Kb, Vt);
  attn_kernel<<<dim3(512, 1, 1), 512, 81920, stream>>>(Qb, Kb, Vt);
  outproj_kernel<<<dim3(128, 1, 1), 256, 0, stream>>>(Qb, Wot, bo, out);
}

// Round 6
// 154.450 us; speedup vs baseline: 1.6002x; 1.6002x over previous
//
#include <hip/hip_runtime.h>

typedef __bf16 bf16;
typedef __bf16 bf16x4 __attribute__((ext_vector_type(4)));
typedef __bf16 bf16x8 __attribute__((ext_vector_type(8)));
typedef float f32x4 __attribute__((ext_vector_type(4)));

#define MFMA16(a, b, c) __builtin_amdgcn_mfma_f32_16x16x32_bf16((a), (b), (c), 0, 0, 0)

__device__ __forceinline__ int swz16(int r, int c) { return (c ^ (r & 15)); }
__device__ __forceinline__ int swz8(int r, int c) { return (c ^ (r & 7)); }

// ---- fused weight transposes: z=0..2 Wq/Wk/Wv (128x1024), z=3 Wo (1024x128) ----
__global__ __launch_bounds__(256) void trW_kernel(
    const float* __restrict__ Wq, const float* __restrict__ Wk,
    const float* __restrict__ Wv, const float* __restrict__ Wo,
    bf16* __restrict__ outbase) {
  __shared__ bf16 tile[32][33];
  const int z = blockIdx.z;
  const float* ib = (z == 0) ? Wq : (z == 1) ? Wk : (z == 2) ? Wv : Wo;
  bf16* ob = outbase + (size_t)z * 131072;
  const int R = (z < 3) ? 128 : 1024;   // input rows
  const int C = (z < 3) ? 1024 : 128;   // input cols
  int r0 = (z < 3) ? blockIdx.y * 32 : blockIdx.x * 32;
  int c0 = (z < 3) ? blockIdx.x * 32 : blockIdx.y * 32;
  int tx = threadIdx.x & 31, ty = threadIdx.x >> 5;
#pragma unroll
  for (int i = 0; i < 4; ++i) {
    int r = ty + i * 8;
    tile[r][tx] = (bf16)ib[(size_t)(r0 + r) * C + (c0 + tx)];
  }
  __syncthreads();
#pragma unroll
  for (int i = 0; i < 4; ++i) {
    int r = ty + i * 8;
    ob[(size_t)(c0 + r) * R + (r0 + tx)] = tile[tx][r];
  }
}

// -------- QKV projection: fp32 x [4096x128] @ Wt -> Q/K [bh][t][d], V [bh][d][t] ----
__global__ __launch_bounds__(256) void proj_gemm(
    const float* __restrict__ x, const bf16* __restrict__ Wqt,
    const bf16* __restrict__ Wkt, const bf16* __restrict__ Wvt,
    bf16* __restrict__ Qb, bf16* __restrict__ Kb, bf16* __restrict__ Vt) {
  __shared__ __align__(16) bf16 As[128 * 128];
  __shared__ __align__(16) bf16 Bs[128 * 128];
  const int mt = blockIdx.x;  // 32 tiles of 128 token-rows
  const int nt = blockIdx.y;  // 24 tiles of 128 cols (8 per matrix)
  const int matid = nt >> 3, h = nt & 7;
  const bf16* W = (matid == 0) ? Wqt : (matid == 1) ? Wkt : Wvt;
  const int tid = threadIdx.x;
  const bf16* sb = W + (size_t)h * 128 * 128;
#pragma unroll
  for (int i = 0; i < 8; ++i) {  // stage x tile, fp32 -> bf16
    int c = tid + i * 256;
    int r = c >> 4, cc = c & 15;
    const f32x4* p = (const f32x4*)(x + (size_t)(mt * 128 + r) * 128 + cc * 8);
    f32x4 a = p[0], b = p[1];
    bf16x8 o;
#pragma unroll
    for (int j = 0; j < 4; ++j) { o[j] = (bf16)a[j]; o[4 + j] = (bf16)b[j]; }
    *(bf16x8*)&As[r * 128 + swz16(r, cc) * 8] = o;
  }
#pragma unroll
  for (int i = 0; i < 8; ++i) {
    int c = tid + i * 256;
    int r = c >> 4, cc = c & 15;
    *(bf16x8*)&Bs[r * 128 + swz16(r, cc) * 8] = *(const bf16x8*)(sb + (size_t)r * 128 + cc * 8);
  }
  __syncthreads();
  const int wave = tid >> 6, lane = tid & 63;
  const int wr = (wave >> 1) * 64, wc = (wave & 1) * 64;
  const int lr = lane & 15, lkb = lane >> 4;
  const f32x4 FZ = {0.f, 0.f, 0.f, 0.f};
  f32x4 acc[4][4];
#pragma unroll
  for (int mf = 0; mf < 4; ++mf)
#pragma unroll
    for (int nf = 0; nf < 4; ++nf) acc[mf][nf] = FZ;
  const bool qk = (matid < 2);
#pragma unroll
  for (int ks = 0; ks < 4; ++ks) {
    bf16x8 a[4], b[4];
#pragma unroll
    for (int mf = 0; mf < 4; ++mf) {
      int r = wr + mf * 16 + lr;
      a[mf] = *(const bf16x8*)&As[r * 128 + swz16(r, ks * 4 + lkb) * 8];
    }
#pragma unroll
    for (int nf = 0; nf < 4; ++nf) {
      int r = wc + nf * 16 + lr;
      b[nf] = *(const bf16x8*)&Bs[r * 128 + swz16(r, ks * 4 + lkb) * 8];
    }
    if (qk) {  // transposed output: C[row=n][col=m] -> vectorizable d-runs
#pragma unroll
      for (int mf = 0; mf < 4; ++mf)
#pragma unroll
        for (int nf = 0; nf < 4; ++nf) acc[mf][nf] = MFMA16(b[nf], a[mf], acc[mf][nf]);
    } else {
#pragma unroll
      for (int mf = 0; mf < 4; ++mf)
#pragma unroll
        for (int nf = 0; nf < 4; ++nf) acc[mf][nf] = MFMA16(a[mf], b[nf], acc[mf][nf]);
    }
  }
  const int rb = lkb * 4;
  if (qk) {  // Q/K: [bh][t][d]; lane holds 4 consecutive d for one token
    bf16* Out = (matid == 0) ? Qb : Kb;
#pragma unroll
    for (int mf = 0; mf < 4; ++mf)
#pragma unroll
      for (int nf = 0; nf < 4; ++nf) {
        int m = mt * 128 + wr + mf * 16 + lr;  // token
        int d0 = wc + nf * 16 + rb;            // 4 consecutive dims
        int bb = m >> 11, t = m & 2047;
        bf16x4 vv;
#pragma unroll
        for (int r = 0; r < 4; ++r) vv[r] = (bf16)acc[mf][nf][r];
        *(bf16x4*)(Out + ((size_t)(bb * 8 + h) * 2048 + t) * 128 + d0) = vv;
      }
  } else {  // V: [bh][d][t]; lane holds 4 consecutive tokens for one dim
#pragma unroll
    for (int mf = 0; mf < 4; ++mf)
#pragma unroll
      for (int nf = 0; nf < 4; ++nf) {
        int d = wc + nf * 16 + lr;
        int m0 = mt * 128 + wr + mf * 16 + rb;
        int bb = m0 >> 11, t0 = m0 & 2047;
        bf16x4 vv;
#pragma unroll
        for (int r = 0; r < 4; ++r) vv[r] = (bf16)acc[mf][nf][r];
        *(bf16x4*)(Vt + ((size_t)(bb * 8 + h) * 128 + d) * 2048 + t0) = vv;
      }
  }
}

// ---- causal flash attention: 512 blocks x 512 thr; in-block kv-split (2 groups) ----
// group g of waves handles kv tiles [g? h0:0, g? nT:h0); merged at the end via LDS.
__global__ __launch_bounds__(512) void attn_kernel(
    bf16* __restrict__ Qb, const bf16* __restrict__ Kb, const bf16* __restrict__ Vt) {
  extern __shared__ char smem[];  // 81920 B
  const f32x4 FZ = {0.f, 0.f, 0.f, 0.f};
  const int bid = blockIdx.x;
  const int qt = 31 - (bid >> 4);
  const int bh = bid & 15;
  const int nT = qt + 1;
  const int h0 = (nT + 1) >> 1, h1 = nT - h0;
  const bf16* Qh = Qb + (size_t)bh * 2048 * 128;
  bf16* Qw = Qb + (size_t)bh * 2048 * 128;
  const bf16* Kh = Kb + (size_t)bh * 2048 * 128;
  const bf16* Vh = Vt + (size_t)bh * 128 * 2048;
  const int tid = threadIdx.x, wave = tid >> 6, lane = tid & 63;
  const int g = tid >> 8;            // wave-group 0/1
  const int tg = tid & 255;          // tid within group
  const int gw = wave & 3;           // wave within group
  const int lr = lane & 15, lkb = lane >> 4, rb = lkb * 4;
  const float SCL = 0.12751744f;     // log2(e)/sqrt(128)
  const int qrow = qt * 64 + gw * 16;
  const int hg = g ? h1 : h0;        // this group's tile count
  const int tbase = g ? h0 : 0;      // this group's first kv tile

  bf16* Ks = (bf16*)(smem + g * 16384);
  bf16* Vs = (bf16*)(smem + 32768 + g * 16384);
  bf16* Ps = (bf16*)(smem + 65536) + wave * 1024;

  // loop-invariant staging addresses (per group: 256 threads stage 64x128 K, 128x64 V)
  const int krow = tg >> 4, kcc = tg & 15;
  bf16* kdst = &Ks[krow * 128 + (kcc ^ krow) * 8];
  const bf16* ksrc0 = Kh + (size_t)krow * 128 + kcc * 8;
  const int vrow = tg >> 3, vcc = tg & 7;
  bf16* vdst = &Vs[vrow * 64 + (vcc ^ (vrow & 7)) * 8];
  const bf16* vsrc0 = Vh + (size_t)vrow * 2048 + vcc * 8;

  float mrun[4], lrun[4];
  f32x4 O[8];
  bf16x8 qf[4];
#pragma unroll
  for (int r = 0; r < 4; ++r) { mrun[r] = -__builtin_inff(); lrun[r] = 0.f; }
#pragma unroll
  for (int nf = 0; nf < 8; ++nf) O[nf] = FZ;
#pragma unroll
  for (int ks = 0; ks < 4; ++ks)
    qf[ks] = *(const bf16x8*)(Qh + (size_t)(qrow + lr) * 128 + ks * 32 + lkb * 8);

  bf16x8 kpre[4], vpre[4];
  if (hg > 0) {  // prefetch this group's first tile
    const size_t ko = (size_t)tbase * 8192, vo = (size_t)tbase * 64;
#pragma unroll
    for (int i = 0; i < 4; ++i) kpre[i] = *(const bf16x8*)(ksrc0 + ko + i * 2048);
#pragma unroll
    for (int i = 0; i < 4; ++i) vpre[i] = *(const bf16x8*)(vsrc0 + vo + i * 65536);
  }

  for (int it = 0; it < h0; ++it) {
    const bool act = (it < hg);
    const int kvt = tbase + it;
    __syncthreads();  // previous iteration's LDS reads complete
    if (act) {
#pragma unroll
      for (int i = 0; i < 4; ++i) *(bf16x8*)(kdst + i * 2048) = kpre[i];
#pragma unroll
      for (int i = 0; i < 4; ++i) *(bf16x8*)(vdst + i * 2048) = vpre[i];
    }
    __syncthreads();  // staged tiles visible
    if (it + 1 < hg) {  // issue next tile's loads; land during compute
      const size_t ko = (size_t)(kvt + 1) * 8192, vo = (size_t)(kvt + 1) * 64;
#pragma unroll
      for (int i = 0; i < 4; ++i) kpre[i] = *(const bf16x8*)(ksrc0 + ko + i * 2048);
#pragma unroll
      for (int i = 0; i < 4; ++i) vpre[i] = *(const bf16x8*)(vsrc0 + vo + i * 65536);
    }
    if (!act) continue;
    // S = Q K^T (raw, unscaled)
    f32x4 s[4];
#pragma unroll
    for (int nf = 0; nf < 4; ++nf) s[nf] = FZ;
#pragma unroll
    for (int ks = 0; ks < 4; ++ks) {
#pragma unroll
      for (int nf = 0; nf < 4; ++nf) {
        int r = nf * 16 + lr;
        bf16x8 b = *(const bf16x8*)&Ks[r * 128 + swz16(r, ks * 4 + lkb) * 8];
        s[nf] = MFMA16(qf[ks], b, s[nf]);
      }
    }
    // raw-domain max (mask only on the diagonal tile; uniform branch)
    float pmax[4];
#pragma unroll
    for (int r = 0; r < 4; ++r) pmax[r] = -__builtin_inff();
    if (kvt == qt) {
#pragma unroll
      for (int nf = 0; nf < 4; ++nf) {
        int colg = (qt << 6) + nf * 16 + lr;
#pragma unroll
        for (int r = 0; r < 4; ++r) {
          int rowg = qrow + rb + r;
          float v = (colg > rowg) ? -__builtin_inff() : s[nf][r];
          s[nf][r] = v;
          pmax[r] = fmaxf(pmax[r], v);
        }
      }
    } else {
#pragma unroll
      for (int nf = 0; nf < 4; ++nf)
#pragma unroll
        for (int r = 0; r < 4; ++r) pmax[r] = fmaxf(pmax[r], s[nf][r]);
    }
#pragma unroll
    for (int r = 0; r < 4; ++r) {  // reduce across the 16 lanes sharing these rows
      float v = pmax[r];
      v = fmaxf(v, __shfl_xor(v, 1, 64));
      v = fmaxf(v, __shfl_xor(v, 2, 64));
      v = fmaxf(v, __shfl_xor(v, 4, 64));
      v = fmaxf(v, __shfl_xor(v, 8, 64));
      pmax[r] = v;
    }
    float alpha[4];
#pragma unroll
    for (int r = 0; r < 4; ++r) {
      float mnew = fmaxf(mrun[r], pmax[r] * SCL);
      alpha[r] = exp2f(mrun[r] - mnew);
      mrun[r] = mnew;
    }
    float psum[4] = {0.f, 0.f, 0.f, 0.f};
#pragma unroll
    for (int nf = 0; nf < 4; ++nf)
#pragma unroll
      for (int r = 0; r < 4; ++r) {
        float p = exp2f(__builtin_fmaf(s[nf][r], SCL, -mrun[r]));
        s[nf][r] = p;
        psum[r] += p;
      }
#pragma unroll
    for (int r = 0; r < 4; ++r) {
      float v = psum[r];
      v += __shfl_xor(v, 1, 64);
      v += __shfl_xor(v, 2, 64);
      v += __shfl_xor(v, 4, 64);
      v += __shfl_xor(v, 8, 64);
      lrun[r] = lrun[r] * alpha[r] + v;
    }
#pragma unroll
    for (int nf = 0; nf < 8; ++nf) {
#pragma unroll
      for (int r = 0; r < 4; ++r) O[nf][r] *= alpha[r];
    }
    // P -> per-wave LDS (re-fragment for PV A-operand); wave-private, no barrier
#pragma unroll
    for (int nf = 0; nf < 4; ++nf) {
#pragma unroll
      for (int r = 0; r < 4; ++r) {
        int row = rb + r;
        int col = nf * 16 + lr;
        Ps[row * 64 + swz8(row, col >> 3) * 8 + (col & 7)] = (bf16)s[nf][r];
      }
    }
    // O += P @ V
#pragma unroll
    for (int ks2 = 0; ks2 < 2; ++ks2) {
      bf16x8 a = *(const bf16x8*)&Ps[lr * 64 + swz8(lr, ks2 * 4 + lkb) * 8];
#pragma unroll
      for (int nf = 0; nf < 8; ++nf) {
        int r = nf * 16 + lr;
        bf16x8 b = *(const bf16x8*)&Vs[r * 64 + swz8(r, ks2 * 4 + lkb) * 8];
        O[nf] = MFMA16(a, b, O[nf]);
      }
    }
  }

  // ---- merge the two groups' (m, l, O) via LDS, then write over Q rows ----
  float* Om = (float*)smem;            // [64][132] padded stride (bank-conflict-free)
  float* Lm = (float*)(smem + 33792);  // [64]
  float* Ll = (float*)(smem + 34304);  // [64]
  __syncthreads();  // all compute (LDS reads) done
  if (g == 1) {
#pragma unroll
    for (int nf = 0; nf < 8; ++nf)
#pragma unroll
      for (int r = 0; r < 4; ++r)
        Om[(gw * 16 + rb + r) * 132 + nf * 16 + lr] = O[nf][r];
    if (lr == 0) {
#pragma unroll
      for (int r = 0; r < 4; ++r) {
        Lm[gw * 16 + rb + r] = mrun[r];
        Ll[gw * 16 + rb + r] = lrun[r];
      }
    }
  }
  __syncthreads();
  if (g == 0) {
#pragma unroll
    for (int r = 0; r < 4; ++r) {
      int row = gw * 16 + rb + r;
      float m1 = Lm[row], l1 = Ll[row];
      float m = fmaxf(mrun[r], m1);
      float a0 = exp2f(mrun[r] - m), a1 = exp2f(m1 - m);
      float inv = 1.f / (lrun[r] * a0 + l1 * a1);
      int t = qrow + rb + r;
#pragma unroll
      for (int nf = 0; nf < 8; ++nf) {
        float o1 = Om[row * 132 + nf * 16 + lr];
        Qw[(size_t)t * 128 + nf * 16 + lr] =
            (bf16)((O[nf][r] * a0 + o1 * a1) * inv);
      }
    }
  }
}

// ------- output projection: AO [bh][t][128] @ Wot [128][1024] + bo -> fp32 out ------
__global__ __launch_bounds__(256) void outproj_kernel(
    const bf16* __restrict__ AO, const bf16* __restrict__ Wot,
    const float* __restrict__ bo, float* __restrict__ out) {
  __shared__ __align__(16) bf16 As[32 * 128];
  __shared__ __align__(16) bf16 Bs[128 * 128];
  const f32x4 FZ = {0.f, 0.f, 0.f, 0.f};
  const int mt = blockIdx.x;  // 128 tiles of 32 rows
  const int tid = threadIdx.x, wave = tid >> 6, lane = tid & 63;
  const int lr = lane & 15, lkb = lane >> 4, rb = lkb * 4;
  const int wr = (wave >> 1) * 16, wc = (wave & 1) * 64;
  f32x4 acc[4];
#pragma unroll
  for (int nf = 0; nf < 4; ++nf) acc[nf] = FZ;
  for (int kt = 0; kt < 8; ++kt) {  // kt == head index (k-chunk of 128)
    __syncthreads();
#pragma unroll
    for (int i = 0; i < 2; ++i) {
      int c = tid + i * 256;
      int r = c >> 4, cc = c & 15;
      int m = mt * 32 + r, bb = m >> 11, t = m & 2047;
      *(bf16x8*)&As[r * 128 + swz16(r, cc) * 8] =
          *(const bf16x8*)(AO + ((size_t)(bb * 8 + kt) * 2048 + t) * 128 + cc * 8);
    }
#pragma unroll
    for (int i = 0; i < 8; ++i) {
      int c = tid + i * 256;
      int r = c >> 4, cc = c & 15;
      *(bf16x8*)&Bs[r * 128 + swz16(r, cc) * 8] =
          *(const bf16x8*)(Wot + (size_t)r * 1024 + kt * 128 + cc * 8);
    }
    __syncthreads();
#pragma unroll
    for (int ks = 0; ks < 4; ++ks) {
      int ra = wr + lr;
      bf16x8 a = *(const bf16x8*)&As[ra * 128 + swz16(ra, ks * 4 + lkb) * 8];
#pragma unroll
      for (int nf = 0; nf < 4; ++nf) {
        int r = wc + nf * 16 + lr;
        bf16x8 b = *(const bf16x8*)&Bs[r * 128 + swz16(r, ks * 4 + lkb) * 8];
        acc[nf] = MFMA16(a, b, acc[nf]);
      }
    }
  }
#pragma unroll
  for (int nf = 0; nf < 4; ++nf)
#pragma unroll
    for (int r = 0; r < 4; ++r) {
      int m = mt * 32 + wr + rb + r;
      int n = wc + nf * 16 + lr;
      out[(size_t)m * 128 + n] = acc[nf][r] + bo[n];
    }
}

extern "C" void kernel_launch(void* const* d_in, const int* in_sizes, int n_in,
                              void* d_out, int out_size, void* d_ws, size_t ws_size,
                              hipStream_t stream) {
  (void)in_sizes; (void)n_in; (void)out_size; (void)ws_size;
  const float* x  = (const float*)d_in[0];   // [4096][128] fp32
  const float* Wq = (const float*)d_in[1];   // [128][1024] fp32
  const float* Wk = (const float*)d_in[2];
  const float* Wv = (const float*)d_in[3];
  const float* Wo = (const float*)d_in[4];   // [1024][128] fp32
  const float* bo = (const float*)d_in[5];   // [128] fp32
  float* out = (float*)d_out;                // [4096][128] fp32

  // ws layout (bf16 elements): total 13,107,200 el = 25 MB
  bf16* ws  = (bf16*)d_ws;
  bf16* Wqt = ws;                 // [3][1024][128] (q,k,v transposed weights)
  bf16* Wkt = Wqt + 131072;
  bf16* Wvt = Wkt + 131072;
  bf16* Wot = Wvt + 131072;       // [128][1024]
  bf16* Qb  = Wot + 131072;       // [16][2048][128]; attn output written in-place
  bf16* Kb  = Qb + 4194304;       // [16][2048][128]
  bf16* Vt  = Kb + 4194304;       // [16][128][2048]

  trW_kernel<<<dim3(32, 4, 4), 256, 0, stream>>>(Wq, Wk, Wv, Wo, Wqt);
  proj_gemm<<<dim3(32, 24, 1), 256, 0, stream>>>(x, Wqt, Wkt, Wvt, Qb, Kb, Vt);
  attn_kernel<<<dim3(512, 1, 1), 512, 81920, stream>>>(Qb, Kb, Vt);
  outproj_kernel<<<dim3(128, 1, 1), 256, 0, stream>>>(Qb, Wot, bo, out);
}

// Round 7
// 148.699 us; speedup vs baseline: 1.6621x; 1.0387x over previous
//
#include <hip/hip_runtime.h>

typedef __bf16 bf16;
typedef __bf16 bf16x4 __attribute__((ext_vector_type(4)));
typedef __bf16 bf16x8 __attribute__((ext_vector_type(8)));
typedef float f32x4 __attribute__((ext_vector_type(4)));
typedef float f32x16 __attribute__((ext_vector_type(16)));
typedef int i32x4 __attribute__((ext_vector_type(4)));

#define MFMA16(a, b, c) __builtin_amdgcn_mfma_f32_16x16x32_bf16((a), (b), (c), 0, 0, 0)
#define MFMA32(a, b, c) __builtin_amdgcn_mfma_f32_32x32x16_bf16((a), (b), (c), 0, 0, 0)

__device__ __forceinline__ int swz16(int r, int c) { return (c ^ (r & 15)); }
__device__ __forceinline__ int swz8(int r, int c) { return (c ^ (r & 7)); }

__device__ __forceinline__ int cvt_pk_bf16(float lo, float hi) {
  int r;
  asm("v_cvt_pk_bf16_f32 %0, %1, %2" : "=v"(r) : "v"(lo), "v"(hi));
  return r;
}

// ---- fused weight transposes: z=0..2 Wq/Wk/Wv (128x1024), z=3 Wo (1024x128) ----
__global__ __launch_bounds__(256) void trW_kernel(
    const float* __restrict__ Wq, const float* __restrict__ Wk,
    const float* __restrict__ Wv, const float* __restrict__ Wo,
    bf16* __restrict__ outbase) {
  __shared__ bf16 tile[32][33];
  const int z = blockIdx.z;
  const float* ib = (z == 0) ? Wq : (z == 1) ? Wk : (z == 2) ? Wv : Wo;
  bf16* ob = outbase + (size_t)z * 131072;
  const int R = (z < 3) ? 128 : 1024;
  const int C = (z < 3) ? 1024 : 128;
  int r0 = (z < 3) ? blockIdx.y * 32 : blockIdx.x * 32;
  int c0 = (z < 3) ? blockIdx.x * 32 : blockIdx.y * 32;
  int tx = threadIdx.x & 31, ty = threadIdx.x >> 5;
#pragma unroll
  for (int i = 0; i < 4; ++i) {
    int r = ty + i * 8;
    tile[r][tx] = (bf16)ib[(size_t)(r0 + r) * C + (c0 + tx)];
  }
  __syncthreads();
#pragma unroll
  for (int i = 0; i < 4; ++i) {
    int r = ty + i * 8;
    ob[(size_t)(c0 + r) * R + (r0 + tx)] = tile[tx][r];
  }
}

// -------- QKV projection: fp32 x [4096x128] @ Wt -> Q/K [bh][t][d], V [bh][d][t] ----
__global__ __launch_bounds__(256) void proj_gemm(
    const float* __restrict__ x, const bf16* __restrict__ Wqt,
    const bf16* __restrict__ Wkt, const bf16* __restrict__ Wvt,
    bf16* __restrict__ Qb, bf16* __restrict__ Kb, bf16* __restrict__ Vt) {
  __shared__ __align__(16) bf16 As[128 * 128];
  __shared__ __align__(16) bf16 Bs[128 * 128];
  const int mt = blockIdx.x;
  const int nt = blockIdx.y;
  const int matid = nt >> 3, h = nt & 7;
  const bf16* W = (matid == 0) ? Wqt : (matid == 1) ? Wkt : Wvt;
  const int tid = threadIdx.x;
  const bf16* sb = W + (size_t)h * 128 * 128;
#pragma unroll
  for (int i = 0; i < 8; ++i) {  // stage x tile, fp32 -> bf16
    int c = tid + i * 256;
    int r = c >> 4, cc = c & 15;
    const f32x4* p = (const f32x4*)(x + (size_t)(mt * 128 + r) * 128 + cc * 8);
    f32x4 a = p[0], b = p[1];
    bf16x8 o;
#pragma unroll
    for (int j = 0; j < 4; ++j) { o[j] = (bf16)a[j]; o[4 + j] = (bf16)b[j]; }
    *(bf16x8*)&As[r * 128 + swz16(r, cc) * 8] = o;
  }
#pragma unroll
  for (int i = 0; i < 8; ++i) {
    int c = tid + i * 256;
    int r = c >> 4, cc = c & 15;
    *(bf16x8*)&Bs[r * 128 + swz16(r, cc) * 8] = *(const bf16x8*)(sb + (size_t)r * 128 + cc * 8);
  }
  __syncthreads();
  const int wave = tid >> 6, lane = tid & 63;
  const int wr = (wave >> 1) * 64, wc = (wave & 1) * 64;
  const int lr = lane & 15, lkb = lane >> 4;
  const f32x4 FZ = {0.f, 0.f, 0.f, 0.f};
  f32x4 acc[4][4];
#pragma unroll
  for (int mf = 0; mf < 4; ++mf)
#pragma unroll
    for (int nf = 0; nf < 4; ++nf) acc[mf][nf] = FZ;
  const bool qk = (matid < 2);
#pragma unroll
  for (int ks = 0; ks < 4; ++ks) {
    bf16x8 a[4], b[4];
#pragma unroll
    for (int mf = 0; mf < 4; ++mf) {
      int r = wr + mf * 16 + lr;
      a[mf] = *(const bf16x8*)&As[r * 128 + swz16(r, ks * 4 + lkb) * 8];
    }
#pragma unroll
    for (int nf = 0; nf < 4; ++nf) {
      int r = wc + nf * 16 + lr;
      b[nf] = *(const bf16x8*)&Bs[r * 128 + swz16(r, ks * 4 + lkb) * 8];
    }
    if (qk) {
#pragma unroll
      for (int mf = 0; mf < 4; ++mf)
#pragma unroll
        for (int nf = 0; nf < 4; ++nf) acc[mf][nf] = MFMA16(b[nf], a[mf], acc[mf][nf]);
    } else {
#pragma unroll
      for (int mf = 0; mf < 4; ++mf)
#pragma unroll
        for (int nf = 0; nf < 4; ++nf) acc[mf][nf] = MFMA16(a[mf], b[nf], acc[mf][nf]);
    }
  }
  const int rb = lkb * 4;
  if (qk) {  // Q/K: [bh][t][d]
    bf16* Out = (matid == 0) ? Qb : Kb;
#pragma unroll
    for (int mf = 0; mf < 4; ++mf)
#pragma unroll
      for (int nf = 0; nf < 4; ++nf) {
        int m = mt * 128 + wr + mf * 16 + lr;
        int d0 = wc + nf * 16 + rb;
        int bb = m >> 11, t = m & 2047;
        bf16x4 vv;
#pragma unroll
        for (int r = 0; r < 4; ++r) vv[r] = (bf16)acc[mf][nf][r];
        *(bf16x4*)(Out + ((size_t)(bb * 8 + h) * 2048 + t) * 128 + d0) = vv;
      }
  } else {  // V: [bh][d][t]
#pragma unroll
    for (int mf = 0; mf < 4; ++mf)
#pragma unroll
      for (int nf = 0; nf < 4; ++nf) {
        int d = wc + nf * 16 + lr;
        int m0 = mt * 128 + wr + mf * 16 + rb;
        int bb = m0 >> 11, t0 = m0 & 2047;
        bf16x4 vv;
#pragma unroll
        for (int r = 0; r < 4; ++r) vv[r] = (bf16)acc[mf][nf][r];
        *(bf16x4*)(Vt + ((size_t)(bb * 8 + h) * 128 + d) * 2048 + t0) = vv;
      }
  }
}

// ---- causal flash attention: swapped-QK 32x32 MFMA, O^T orientation, kv-split ----
// 512 blocks x 256 thr (4 waves = 2 groups x 2 waves); each wave owns 32 q-rows.
// QK: p = mfma(K_frag, Q_frag) -> lane = q-col, regs = kv-rows (softmax lane-local).
// PV: O^T = mfma(V^T_frag, P_frag) -> lane = q-col, regs = d-rows.
__global__ __launch_bounds__(256) void attn_kernel(
    bf16* __restrict__ Qb, const bf16* __restrict__ Kb, const bf16* __restrict__ Vt) {
  extern __shared__ char smem[];  // 65536 B: 2 groups x (Ks 16K + Vs 16K)
  const int bid = blockIdx.x;
  const int qt = 31 - (bid >> 4);  // LPT: big tiles first
  const int bh = bid & 15;
  const int nT = qt + 1;
  const int h0 = (nT + 1) >> 1, h1 = nT - h0;
  const bf16* Qh = Qb + (size_t)bh * 2048 * 128;
  bf16* Qw = Qb + (size_t)bh * 2048 * 128;
  const bf16* Kh = Kb + (size_t)bh * 2048 * 128;
  const bf16* Vh = Vt + (size_t)bh * 128 * 2048;
  const int tid = threadIdx.x, lane = tid & 63;
  const int g = tid >> 7;           // group 0/1
  const int tg = tid & 127;         // tid in group
  const int wig = (tid >> 6) & 1;   // wave in group
  const int lq = lane & 31;         // q-col
  const int hi = lane >> 5;
  const int q0w = qt * 64 + wig * 32;
  const int hg = g ? h1 : h0;
  const int tbase = g ? h0 : 0;
  const float SCL = 0.12751744f;    // log2(e)/sqrt(128)

  bf16* Ks = (bf16*)(smem + g * 32768);           // [64][128] swizzled chunks
  bf16* Vs = (bf16*)(smem + g * 32768 + 16384);   // [128][64] swizzled chunks

  // staging geometry: 128 threads/group; K: 8 rows x 16 chunks per iter (x8);
  // V: 16 rows x 8 chunks per iter (x8)
  const int krow = tg >> 4, kcc = tg & 15;
  const int kchb = kcc ^ krow;
  const bf16* ksrc0 = Kh + (size_t)krow * 128 + kcc * 8;
  const int vrow = tg >> 3, vcc = tg & 7;
  bf16* vdst0 = Vs + vrow * 64 + (vcc ^ (vrow & 7)) * 8;
  const bf16* vsrc0 = Vh + (size_t)vrow * 2048 + vcc * 8;

  // Q fragments: B-operand [q=lq][d-chunk], 8 K-steps of 16
  bf16x8 qf[8];
#pragma unroll
  for (int ks = 0; ks < 8; ++ks)
    qf[ks] = *(const bf16x8*)(Qh + (size_t)(q0w + lq) * 128 + ks * 16 + hi * 8);

  float mrun = -__builtin_inff(), lrun = 0.f;
  f32x16 O[4];
#pragma unroll
  for (int dt = 0; dt < 4; ++dt)
#pragma unroll
    for (int r = 0; r < 16; ++r) O[dt][r] = 0.f;

  bf16x8 kpre[8], vpre[8];
  if (hg > 0) {
    const size_t ko = (size_t)tbase * 8192, vo = (size_t)tbase * 64;
#pragma unroll
    for (int i = 0; i < 8; ++i) kpre[i] = *(const bf16x8*)(ksrc0 + ko + i * 1024);
#pragma unroll
    for (int i = 0; i < 8; ++i) vpre[i] = *(const bf16x8*)(vsrc0 + vo + i * 32768);
  }

  for (int it = 0; it < h0; ++it) {
    const bool act = (it < hg);
    const int kvt = tbase + it;
    const int kv0 = kvt * 64;
    __syncthreads();  // previous pass's LDS reads complete
    if (act) {
#pragma unroll
      for (int i = 0; i < 8; ++i)
        *(bf16x8*)(Ks + (krow + 8 * i) * 128 + (kchb ^ ((i & 1) << 3)) * 8) = kpre[i];
#pragma unroll
      for (int i = 0; i < 8; ++i) *(bf16x8*)(vdst0 + i * 1024) = vpre[i];
    }
    __syncthreads();  // staged tiles visible
    if (it + 1 < hg) {
      const size_t ko = (size_t)(kvt + 1) * 8192, vo = (size_t)(kvt + 1) * 64;
#pragma unroll
      for (int i = 0; i < 8; ++i) kpre[i] = *(const bf16x8*)(ksrc0 + ko + i * 1024);
#pragma unroll
      for (int i = 0; i < 8; ++i) vpre[i] = *(const bf16x8*)(vsrc0 + vo + i * 32768);
    }
    if (!act) continue;

    // ---- QK^T swapped: p[row=kv, col=q] ----
    f32x16 p0, p1;
#pragma unroll
    for (int r = 0; r < 16; ++r) { p0[r] = 0.f; p1[r] = 0.f; }
#pragma unroll
    for (int ks = 0; ks < 8; ++ks) {
      int c = (ks * 2 + hi);
      bf16x8 ka = *(const bf16x8*)&Ks[lq * 128 + (c ^ (lq & 15)) * 8];
      bf16x8 kb = *(const bf16x8*)&Ks[(32 + lq) * 128 + (c ^ (lq & 15)) * 8];
      p0 = MFMA32(ka, qf[ks], p0);
      p1 = MFMA32(kb, qf[ks], p1);
    }
    // ---- causal mask (diagonal tile only) ----
    if (kvt == qt) {
      const int qg = q0w + lq;
#pragma unroll
      for (int r = 0; r < 16; ++r) {
        int kvr = kv0 + (r & 3) + 8 * (r >> 2) + 4 * hi;
        if (kvr > qg) p0[r] = -__builtin_inff();
        if (kvr + 32 > qg) p1[r] = -__builtin_inff();
      }
    }
    // ---- online softmax: lane-local reduce + one cross-half shuffle ----
    float pm = -__builtin_inff();
#pragma unroll
    for (int r = 0; r < 16; ++r) pm = fmaxf(pm, fmaxf(p0[r], p1[r]));
    pm = fmaxf(pm, __shfl_xor(pm, 32, 64));
    float mnew = fmaxf(mrun, pm * SCL);
    float alpha = exp2f(mrun - mnew);
    mrun = mnew;
    float ps = 0.f;
#pragma unroll
    for (int r = 0; r < 16; ++r) {
      float a = exp2f(__builtin_fmaf(p0[r], SCL, -mnew));
      float b = exp2f(__builtin_fmaf(p1[r], SCL, -mnew));
      p0[r] = a; p1[r] = b;
      ps += a + b;
    }
    ps += __shfl_xor(ps, 32, 64);
    lrun = lrun * alpha + ps;
#pragma unroll
    for (int dt = 0; dt < 4; ++dt)
#pragma unroll
      for (int r = 0; r < 16; ++r) O[dt][r] *= alpha;

    // ---- P -> bf16 B-frags in-register (cvt_pk + cross-half shuffles) ----
    int w[16];
#pragma unroll
    for (int i = 0; i < 8; ++i) w[i] = cvt_pk_bf16(p0[2 * i], p0[2 * i + 1]);
#pragma unroll
    for (int i = 0; i < 8; ++i) w[8 + i] = cvt_pk_bf16(p1[2 * i], p1[2 * i + 1]);
    bf16x8 pa[4];
#pragma unroll
    for (int t4 = 0; t4 < 4; ++t4) {  // t4 = kv-16 step
      int b0 = t4 * 4;                // words w[b0..b0+3]
      int e0 = __shfl_xor(w[b0 + 0], 32, 64);
      int e1 = __shfl_xor(w[b0 + 1], 32, 64);
      int e2 = __shfl_xor(w[b0 + 2], 32, 64);
      int e3 = __shfl_xor(w[b0 + 3], 32, 64);
      i32x4 f;
      f[0] = hi ? e2 : w[b0 + 0];
      f[1] = hi ? e3 : w[b0 + 1];
      f[2] = hi ? w[b0 + 2] : e0;
      f[3] = hi ? w[b0 + 3] : e1;
      pa[t4] = __builtin_bit_cast(bf16x8, f);
    }
    // ---- O^T += V^T @ P^T ----
#pragma unroll
    for (int dt = 0; dt < 4; ++dt) {
      int rr = dt * 32 + lq;
#pragma unroll
      for (int ks2 = 0; ks2 < 4; ++ks2) {
        bf16x8 va = *(const bf16x8*)&Vs[rr * 64 + ((ks2 * 2 + hi) ^ (rr & 7)) * 8];
        O[dt] = MFMA32(va, pa[ks2], O[dt]);
      }
    }
  }

  // ---- merge groups via LDS (O^T layout: Om[d][qq]), then write over Q rows ----
  float* Om = (float*)smem;                 // [128][64] f32
  float* Lm = (float*)(smem + 32768);       // [64]
  float* Ll = (float*)(smem + 32768 + 256); // [64]
  const int qq = wig * 32 + lq;
  __syncthreads();
  if (g == 1) {
#pragma unroll
    for (int dt = 0; dt < 4; ++dt)
#pragma unroll
      for (int r = 0; r < 16; ++r)
        Om[(dt * 32 + (r & 3) + 8 * (r >> 2) + 4 * hi) * 64 + qq] = O[dt][r];
    if (!hi) { Lm[qq] = mrun; Ll[qq] = lrun; }
  }
  __syncthreads();
  if (g == 0) {
    float m1 = Lm[qq], l1 = Ll[qq];
    float mf = fmaxf(mrun, m1);
    float a0 = exp2f(mrun - mf), a1 = exp2f(m1 - mf);
    float inv = 1.f / (lrun * a0 + l1 * a1);
    bf16* qwrow = Qw + (size_t)(q0w + lq) * 128;
#pragma unroll
    for (int dt = 0; dt < 4; ++dt) {
#pragma unroll
      for (int rq = 0; rq < 4; ++rq) {
        bf16x4 vv;
#pragma unroll
        for (int j = 0; j < 4; ++j) {
          int r = rq * 4 + j;
          float o1 = Om[(dt * 32 + j + 8 * rq + 4 * hi) * 64 + qq];
          vv[j] = (bf16)((O[dt][r] * a0 + o1 * a1) * inv);
        }
        *(bf16x4*)(qwrow + dt * 32 + 8 * rq + 4 * hi) = vv;
      }
    }
  }
}

// ------- output projection: AO [bh][t][128] @ Wot [128][1024] + bo -> fp32 out ------
__global__ __launch_bounds__(256) void outproj_kernel(
    const bf16* __restrict__ AO, const bf16* __restrict__ Wot,
    const float* __restrict__ bo, float* __restrict__ out) {
  __shared__ __align__(16) bf16 As[16 * 128];
  __shared__ __align__(16) bf16 Bs[128 * 128];
  const f32x4 FZ = {0.f, 0.f, 0.f, 0.f};
  const int mt = blockIdx.x;  // 256 tiles of 16 rows
  const int tid = threadIdx.x, wave = tid >> 6, lane = tid & 63;
  const int lr = lane & 15, lkb = lane >> 4, rb = lkb * 4;
  const int wc = wave * 32;
  f32x4 acc[2];
  acc[0] = FZ; acc[1] = FZ;
  for (int kt = 0; kt < 8; ++kt) {  // kt == head index
    __syncthreads();
    {
      int r = tid >> 4, cc = tid & 15;
      int m = mt * 16 + r, bb = m >> 11, t = m & 2047;
      *(bf16x8*)&As[r * 128 + swz16(r, cc) * 8] =
          *(const bf16x8*)(AO + ((size_t)(bb * 8 + kt) * 2048 + t) * 128 + cc * 8);
    }
#pragma unroll
    for (int i = 0; i < 8; ++i) {
      int c = tid + i * 256;
      int r = c >> 4, cc = c & 15;
      *(bf16x8*)&Bs[r * 128 + swz16(r, cc) * 8] =
          *(const bf16x8*)(Wot + (size_t)r * 1024 + kt * 128 + cc * 8);
    }
    __syncthreads();
#pragma unroll
    for (int ks = 0; ks < 4; ++ks) {
      bf16x8 a = *(const bf16x8*)&As[lr * 128 + swz16(lr, ks * 4 + lkb) * 8];
#pragma unroll
      for (int nf = 0; nf < 2; ++nf) {
        int r = wc + nf * 16 + lr;
        bf16x8 b = *(const bf16x8*)&Bs[r * 128 + swz16(r, ks * 4 + lkb) * 8];
        acc[nf] = MFMA16(a, b, acc[nf]);
      }
    }
  }
#pragma unroll
  for (int nf = 0; nf < 2; ++nf)
#pragma unroll
    for (int r = 0; r < 4; ++r) {
      int m = mt * 16 + rb + r;
      int n = wc + nf * 16 + lr;
      out[(size_t)m * 128 + n] = acc[nf][r] + bo[n];
    }
}

extern "C" void kernel_launch(void* const* d_in, const int* in_sizes, int n_in,
                              void* d_out, int out_size, void* d_ws, size_t ws_size,
                              hipStream_t stream) {
  (void)in_sizes; (void)n_in; (void)out_size; (void)ws_size;
  const float* x  = (const float*)d_in[0];
  const float* Wq = (const float*)d_in[1];
  const float* Wk = (const float*)d_in[2];
  const float* Wv = (const float*)d_in[3];
  const float* Wo = (const float*)d_in[4];
  const float* bo = (const float*)d_in[5];
  float* out = (float*)d_out;

  bf16* ws  = (bf16*)d_ws;
  bf16* Wqt = ws;                 // [3][1024][128]
  bf16* Wkt = Wqt + 131072;
  bf16* Wvt = Wkt + 131072;
  bf16* Wot = Wvt + 131072;       // [128][1024]
  bf16* Qb  = Wot + 131072;       // [16][2048][128]; attn output in-place
  bf16* Kb  = Qb + 4194304;       // [16][2048][128]
  bf16* Vt  = Kb + 4194304;       // [16][128][2048]

  trW_kernel<<<dim3(32, 4, 4), 256, 0, stream>>>(Wq, Wk, Wv, Wo, Wqt);
  proj_gemm<<<dim3(32, 24, 1), 256, 0, stream>>>(x, Wqt, Wkt, Wvt, Qb, Kb, Vt);
  attn_kernel<<<dim3(512, 1, 1), 256, 65536, stream>>>(Qb, Kb, Vt);
  outproj_kernel<<<dim3(256, 1, 1), 256, 0, stream>>>(Qb, Wot, bo, out);
}

// Round 8
// 146.523 us; speedup vs baseline: 1.6867x; 1.0149x over previous
//
#include <hip/hip_runtime.h>

typedef __bf16 bf16;
typedef __bf16 bf16x4 __attribute__((ext_vector_type(4)));
typedef __bf16 bf16x8 __attribute__((ext_vector_type(8)));
typedef float f32x4 __attribute__((ext_vector_type(4)));
typedef float f32x16 __attribute__((ext_vector_type(16)));
typedef int i32x4 __attribute__((ext_vector_type(4)));

#define MFMA16(a, b, c) __builtin_amdgcn_mfma_f32_16x16x32_bf16((a), (b), (c), 0, 0, 0)
#define MFMA32(a, b, c) __builtin_amdgcn_mfma_f32_32x32x16_bf16((a), (b), (c), 0, 0, 0)

__device__ __forceinline__ int swz16(int r, int c) { return (c ^ (r & 15)); }

__device__ __forceinline__ int cvt_pk_bf16(float lo, float hi) {
  int r;
  asm("v_cvt_pk_bf16_f32 %0, %1, %2" : "=v"(r) : "v"(lo), "v"(hi));
  return r;
}

// ---- fused weight transposes: z=0..2 Wq/Wk/Wv (128x1024), z=3 Wo (1024x128) ----
__global__ __launch_bounds__(256) void trW_kernel(
    const float* __restrict__ Wq, const float* __restrict__ Wk,
    const float* __restrict__ Wv, const float* __restrict__ Wo,
    bf16* __restrict__ outbase) {
  __shared__ bf16 tile[32][33];
  const int z = blockIdx.z;
  const float* ib = (z == 0) ? Wq : (z == 1) ? Wk : (z == 2) ? Wv : Wo;
  bf16* ob = outbase + (size_t)z * 131072;
  const int R = (z < 3) ? 128 : 1024;
  const int C = (z < 3) ? 1024 : 128;
  int r0 = (z < 3) ? blockIdx.y * 32 : blockIdx.x * 32;
  int c0 = (z < 3) ? blockIdx.x * 32 : blockIdx.y * 32;
  int tx = threadIdx.x & 31, ty = threadIdx.x >> 5;
#pragma unroll
  for (int i = 0; i < 4; ++i) {
    int r = ty + i * 8;
    tile[r][tx] = (bf16)ib[(size_t)(r0 + r) * C + (c0 + tx)];
  }
  __syncthreads();
#pragma unroll
  for (int i = 0; i < 4; ++i) {
    int r = ty + i * 8;
    ob[(size_t)(c0 + r) * R + (r0 + tx)] = tile[tx][r];
  }
}

// -------- QKV projection -> fragment-major Q/K [blk32][sub16][hi][lane][8], V likewise
__global__ __launch_bounds__(256) void proj_gemm(
    const float* __restrict__ x, const bf16* __restrict__ Wqt,
    const bf16* __restrict__ Wkt, const bf16* __restrict__ Wvt,
    bf16* __restrict__ Qf, bf16* __restrict__ Kf, bf16* __restrict__ Vf) {
  __shared__ __align__(16) bf16 As[128 * 128];
  __shared__ __align__(16) bf16 Bs[128 * 128];
  const int mt = blockIdx.x;
  const int nt = blockIdx.y;
  const int matid = nt >> 3, h = nt & 7;
  const bf16* W = (matid == 0) ? Wqt : (matid == 1) ? Wkt : Wvt;
  const int tid = threadIdx.x;
  const bf16* sb = W + (size_t)h * 128 * 128;
#pragma unroll
  for (int i = 0; i < 8; ++i) {  // stage x tile, fp32 -> bf16
    int c = tid + i * 256;
    int r = c >> 4, cc = c & 15;
    const f32x4* p = (const f32x4*)(x + (size_t)(mt * 128 + r) * 128 + cc * 8);
    f32x4 a = p[0], b = p[1];
    bf16x8 o;
#pragma unroll
    for (int j = 0; j < 4; ++j) { o[j] = (bf16)a[j]; o[4 + j] = (bf16)b[j]; }
    *(bf16x8*)&As[r * 128 + swz16(r, cc) * 8] = o;
  }
#pragma unroll
  for (int i = 0; i < 8; ++i) {
    int c = tid + i * 256;
    int r = c >> 4, cc = c & 15;
    *(bf16x8*)&Bs[r * 128 + swz16(r, cc) * 8] = *(const bf16x8*)(sb + (size_t)r * 128 + cc * 8);
  }
  __syncthreads();
  const int wave = tid >> 6, lane = tid & 63;
  const int wr = (wave >> 1) * 64, wc = (wave & 1) * 64;
  const int lr = lane & 15, lkb = lane >> 4;
  const f32x4 FZ = {0.f, 0.f, 0.f, 0.f};
  f32x4 acc[4][4];
#pragma unroll
  for (int mf = 0; mf < 4; ++mf)
#pragma unroll
    for (int nf = 0; nf < 4; ++nf) acc[mf][nf] = FZ;
  const bool qk = (matid < 2);
#pragma unroll
  for (int ks = 0; ks < 4; ++ks) {
    bf16x8 a[4], b[4];
#pragma unroll
    for (int mf = 0; mf < 4; ++mf) {
      int r = wr + mf * 16 + lr;
      a[mf] = *(const bf16x8*)&As[r * 128 + swz16(r, ks * 4 + lkb) * 8];
    }
#pragma unroll
    for (int nf = 0; nf < 4; ++nf) {
      int r = wc + nf * 16 + lr;
      b[nf] = *(const bf16x8*)&Bs[r * 128 + swz16(r, ks * 4 + lkb) * 8];
    }
    if (qk) {  // transposed C: rows = d, cols = token
#pragma unroll
      for (int mf = 0; mf < 4; ++mf)
#pragma unroll
        for (int nf = 0; nf < 4; ++nf) acc[mf][nf] = MFMA16(b[nf], a[mf], acc[mf][nf]);
    } else {
#pragma unroll
      for (int mf = 0; mf < 4; ++mf)
#pragma unroll
        for (int nf = 0; nf < 4; ++nf) acc[mf][nf] = MFMA16(a[mf], b[nf], acc[mf][nf]);
    }
  }
  const int rb = lkb * 4;
  if (qk) {  // Q/K fragment-major: lane holds token m, 4 consecutive d
    bf16* Out = (matid == 0) ? Qf : Kf;
#pragma unroll
    for (int mf = 0; mf < 4; ++mf)
#pragma unroll
      for (int nf = 0; nf < 4; ++nf) {
        int m = mt * 128 + wr + mf * 16 + lr;
        int d0 = wc + nf * 16 + rb;
        int bb = m >> 11, t = m & 2047;
        bf16x4 vv;
#pragma unroll
        for (int r = 0; r < 4; ++r) vv[r] = (bf16)acc[mf][nf][r];
        size_t e = (size_t)(bb * 8 + h) * 262144
                 + (size_t)(((t >> 5) * 8 + (d0 >> 4)) * 512 + ((d0 >> 3) & 1) * 256
                            + (t & 31) * 8 + (d0 & 7));
        *(bf16x4*)(Out + e) = vv;
      }
  } else {  // V fragment-major: lane holds dim d, 4 consecutive tokens
#pragma unroll
    for (int mf = 0; mf < 4; ++mf)
#pragma unroll
      for (int nf = 0; nf < 4; ++nf) {
        int d = wc + nf * 16 + lr;
        int m0 = mt * 128 + wr + mf * 16 + rb;
        int bb = m0 >> 11, t0 = m0 & 2047;
        bf16x4 vv;
#pragma unroll
        for (int r = 0; r < 4; ++r) vv[r] = (bf16)acc[mf][nf][r];
        size_t e = (size_t)(bb * 8 + h) * 262144
                 + (size_t)((d >> 5) * 65536 + (t0 >> 4) * 512 + ((t0 >> 3) & 1) * 256
                            + (d & 31) * 8 + (t0 & 7));
        *(bf16x4*)(Vf + e) = vv;
      }
  }
}

// ---- causal flash attention: barrier-free main loop, direct-L2 fragment loads ----
// 1024 blocks x 128 thr: one 32-row q-tile per block, kv-split x2 across the 2 waves,
// merged via LDS at the end. Fragment-major layouts make every load 1KB coalesced.
__global__ __launch_bounds__(128) void attn_kernel(
    bf16* __restrict__ Qf, const bf16* __restrict__ Kf, const bf16* __restrict__ Vf) {
  __shared__ float Om[128 * 32];
  __shared__ float Lm[32];
  __shared__ float Ll[32];
  const int bid = blockIdx.x;
  // XCD-aware: bh pinned by bid&7 (2 bh per XCD -> K/V L2-resident);
  // qt grouping {v, 31-v, 32+v, 63-v}: per-CU residency sums constant (66 tiles).
  const int bh = (bid & 7) | (((bid >> 3) & 1) << 3);
  const int j = bid >> 4;
  const int v = j & 15, m4 = j >> 4;
  const int qt = (m4 == 0) ? v : (m4 == 1) ? 31 - v : (m4 == 2) ? 32 + v : 63 - v;
  const int nT = (qt >> 1) + 1;          // 64-kv tiles covering the causal range
  const int h0 = (nT + 1) >> 1, h1 = nT - h0;
  const int tid = threadIdx.x;
  const int g = tid >> 6, lane = tid & 63;
  const int lq = lane & 31, hi = lane >> 5;
  const int q0 = qt * 32;
  const int hg = g ? h1 : h0;
  const int tb = g ? h0 : 0;
  const bf16* Qh = Qf + (size_t)bh * 262144;
  const bf16* Kh = Kf + (size_t)bh * 262144;
  const bf16* Vh = Vf + (size_t)bh * 262144;
  const float SCL = 0.12751744f;         // log2(e)/sqrt(128)
  const int lo = hi * 256 + lq * 8;      // fragment lane offset (elements)

  bf16x8 qf[8];
#pragma unroll
  for (int ks = 0; ks < 8; ++ks)
    qf[ks] = *(const bf16x8*)(Qh + qt * 4096 + ks * 512 + lo);

  float mrun = -__builtin_inff(), lrun = 0.f;
  f32x16 O[4];
#pragma unroll
  for (int dt = 0; dt < 4; ++dt)
#pragma unroll
    for (int r = 0; r < 16; ++r) O[dt][r] = 0.f;

  for (int it = 0; it < hg; ++it) {
    const int kvt = tb + it;
    const int kv0 = kvt * 64;
    const bf16* kbase = Kh + kvt * 8192 + lo;
    // ---- K fragments direct from L2 (coalesced 1KB/instr) ----
    bf16x8 ka[8], kb[8];
#pragma unroll
    for (int i = 0; i < 8; ++i) ka[i] = *(const bf16x8*)(kbase + i * 512);
#pragma unroll
    for (int i = 0; i < 8; ++i) kb[i] = *(const bf16x8*)(kbase + 4096 + i * 512);
    // ---- QK^T swapped: p[row=kv, col=q] ----
    f32x16 p0, p1;
#pragma unroll
    for (int r = 0; r < 16; ++r) { p0[r] = 0.f; p1[r] = 0.f; }
#pragma unroll
    for (int ks = 0; ks < 8; ++ks) p0 = MFMA32(ka[ks], qf[ks], p0);
#pragma unroll
    for (int ks = 0; ks < 8; ++ks) p1 = MFMA32(kb[ks], qf[ks], p1);
    // ---- causal mask (diagonal tile only) ----
    if (kvt == (qt >> 1)) {
      const int qg = q0 + lq;
#pragma unroll
      for (int r = 0; r < 16; ++r) {
        int kvr = kv0 + (r & 3) + 8 * (r >> 2) + 4 * hi;
        if (kvr > qg) p0[r] = -__builtin_inff();
        if (kvr + 32 > qg) p1[r] = -__builtin_inff();
      }
    }
    // ---- online softmax (per-lane q-row; one cross-half shuffle) ----
    float pm = -__builtin_inff();
#pragma unroll
    for (int r = 0; r < 16; ++r) pm = fmaxf(pm, fmaxf(p0[r], p1[r]));
    pm = fmaxf(pm, __shfl_xor(pm, 32, 64));
    float pmS = pm * SCL;
    if (!__all(pmS <= mrun + 8.f)) {   // defer-max: rescale only when max grows
      float mnew = fmaxf(mrun, pmS);
      float alpha = exp2f(mrun - mnew);
      mrun = mnew;
      lrun *= alpha;
#pragma unroll
      for (int dt = 0; dt < 4; ++dt)
#pragma unroll
        for (int r = 0; r < 16; ++r) O[dt][r] *= alpha;
    }
    float ps = 0.f;
#pragma unroll
    for (int r = 0; r < 16; ++r) {
      float a = exp2f(__builtin_fmaf(p0[r], SCL, -mrun));
      float b = exp2f(__builtin_fmaf(p1[r], SCL, -mrun));
      p0[r] = a; p1[r] = b;
      ps += a + b;
    }
    ps += __shfl_xor(ps, 32, 64);
    lrun += ps;
    // ---- P -> bf16 B-frags in-register ----
    int w[16];
#pragma unroll
    for (int i = 0; i < 8; ++i) w[i] = cvt_pk_bf16(p0[2 * i], p0[2 * i + 1]);
#pragma unroll
    for (int i = 0; i < 8; ++i) w[8 + i] = cvt_pk_bf16(p1[2 * i], p1[2 * i + 1]);
    bf16x8 pa[4];
#pragma unroll
    for (int t4 = 0; t4 < 4; ++t4) {
      int b0 = t4 * 4;
      int e0 = __shfl_xor(w[b0 + 0], 32, 64);
      int e1 = __shfl_xor(w[b0 + 1], 32, 64);
      int e2 = __shfl_xor(w[b0 + 2], 32, 64);
      int e3 = __shfl_xor(w[b0 + 3], 32, 64);
      i32x4 f;
      f[0] = hi ? e2 : w[b0 + 0];
      f[1] = hi ? e3 : w[b0 + 1];
      f[2] = hi ? w[b0 + 2] : e0;
      f[3] = hi ? w[b0 + 3] : e1;
      pa[t4] = __builtin_bit_cast(bf16x8, f);
    }
    // ---- O^T += V^T @ P^T (V fragments direct from L2) ----
    const bf16* vbase = Vh + (kvt * 4) * 512 + lo;
#pragma unroll
    for (int dt = 0; dt < 4; ++dt) {
      bf16x8 va0 = *(const bf16x8*)(vbase + dt * 65536 + 0 * 512);
      bf16x8 va1 = *(const bf16x8*)(vbase + dt * 65536 + 1 * 512);
      bf16x8 va2 = *(const bf16x8*)(vbase + dt * 65536 + 2 * 512);
      bf16x8 va3 = *(const bf16x8*)(vbase + dt * 65536 + 3 * 512);
      O[dt] = MFMA32(va0, pa[0], O[dt]);
      O[dt] = MFMA32(va1, pa[1], O[dt]);
      O[dt] = MFMA32(va2, pa[2], O[dt]);
      O[dt] = MFMA32(va3, pa[3], O[dt]);
    }
  }

  // ---- merge the two waves' states via LDS; write output over own Q rows ----
  if (g == 1) {
#pragma unroll
    for (int dt = 0; dt < 4; ++dt)
#pragma unroll
      for (int r = 0; r < 16; ++r)
        Om[(dt * 32 + (r & 3) + 8 * (r >> 2) + 4 * hi) * 32 + lq] = O[dt][r];
    if (!hi) { Lm[lq] = mrun; Ll[lq] = lrun; }
  }
  __syncthreads();
  if (g == 0) {
    float m1 = Lm[lq], l1 = Ll[lq];
    float mF = fmaxf(mrun, m1);
    float a0 = exp2f(mrun - mF), a1 = exp2f(m1 - mF);
    float inv = 1.f / (lrun * a0 + l1 * a1);
    bf16* qw = Qf + (size_t)bh * 262144 + qt * 4096 + lq * 8 + 4 * hi;
#pragma unroll
    for (int dt = 0; dt < 4; ++dt) {
#pragma unroll
      for (int rq = 0; rq < 4; ++rq) {
        bf16x4 vv;
#pragma unroll
        for (int jj = 0; jj < 4; ++jj) {
          int r = rq * 4 + jj;
          int d = dt * 32 + jj + 8 * rq + 4 * hi;
          float o1 = Om[d * 32 + lq];
          vv[jj] = (bf16)((O[dt][r] * a0 + o1 * a1) * inv);
        }
        *(bf16x4*)(qw + (dt * 2 + (rq >> 1)) * 512 + (rq & 1) * 256) = vv;
      }
    }
  }
}

// ------- output projection: AO (fragment-major) @ Wot [128][1024] + bo -> fp32 out --
__global__ __launch_bounds__(256) void outproj_kernel(
    const bf16* __restrict__ AO, const bf16* __restrict__ Wot,
    const float* __restrict__ bo, float* __restrict__ out) {
  __shared__ __align__(16) bf16 As[16 * 128];
  __shared__ __align__(16) bf16 Bs[128 * 128];
  const f32x4 FZ = {0.f, 0.f, 0.f, 0.f};
  const int mt = blockIdx.x;  // 256 tiles of 16 rows
  const int tid = threadIdx.x, wave = tid >> 6, lane = tid & 63;
  const int lr = lane & 15, lkb = lane >> 4, rb = lkb * 4;
  const int wc = wave * 32;
  f32x4 acc[2];
  acc[0] = FZ; acc[1] = FZ;
  for (int kt = 0; kt < 8; ++kt) {  // kt == head index
    __syncthreads();
    {
      int r = tid >> 4, cc = tid & 15;
      int m = mt * 16 + r, bb = m >> 11, t = m & 2047;
      const bf16* src = AO + (size_t)(bb * 8 + kt) * 262144
          + ((t >> 5) * 8 + (cc >> 1)) * 512 + (cc & 1) * 256 + (t & 31) * 8;
      *(bf16x8*)&As[r * 128 + swz16(r, cc) * 8] = *(const bf16x8*)src;
    }
#pragma unroll
    for (int i = 0; i < 8; ++i) {
      int c = tid + i * 256;
      int r = c >> 4, cc = c & 15;
      *(bf16x8*)&Bs[r * 128 + swz16(r, cc) * 8] =
          *(const bf16x8*)(Wot + (size_t)r * 1024 + kt * 128 + cc * 8);
    }
    __syncthreads();
#pragma unroll
    for (int ks = 0; ks < 4; ++ks) {
      bf16x8 a = *(const bf16x8*)&As[lr * 128 + swz16(lr, ks * 4 + lkb) * 8];
#pragma unroll
      for (int nf = 0; nf < 2; ++nf) {
        int r = wc + nf * 16 + lr;
        bf16x8 b = *(const bf16x8*)&Bs[r * 128 + swz16(r, ks * 4 + lkb) * 8];
        acc[nf] = MFMA16(a, b, acc[nf]);
      }
    }
  }
#pragma unroll
  for (int nf = 0; nf < 2; ++nf)
#pragma unroll
    for (int r = 0; r < 4; ++r) {
      int m = mt * 16 + rb + r;
      int n = wc + nf * 16 + lr;
      out[(size_t)m * 128 + n] = acc[nf][r] + bo[n];
    }
}

extern "C" void kernel_launch(void* const* d_in, const int* in_sizes, int n_in,
                              void* d_out, int out_size, void* d_ws, size_t ws_size,
                              hipStream_t stream) {
  (void)in_sizes; (void)n_in; (void)out_size; (void)ws_size;
  const float* x  = (const float*)d_in[0];
  const float* Wq = (const float*)d_in[1];
  const float* Wk = (const float*)d_in[2];
  const float* Wv = (const float*)d_in[3];
  const float* Wo = (const float*)d_in[4];
  const float* bo = (const float*)d_in[5];
  float* out = (float*)d_out;

  bf16* ws  = (bf16*)d_ws;
  bf16* Wqt = ws;                 // [3][1024][128]
  bf16* Wkt = Wqt + 131072;
  bf16* Wvt = Wkt + 131072;
  bf16* Wot = Wvt + 131072;       // [128][1024]
  bf16* Qf  = Wot + 131072;       // [16] fragment-major Q; attn output in-place
  bf16* Kf  = Qf + 4194304;
  bf16* Vf  = Kf + 4194304;

  trW_kernel<<<dim3(32, 4, 4), 256, 0, stream>>>(Wq, Wk, Wv, Wo, Wqt);
  proj_gemm<<<dim3(32, 24, 1), 256, 0, stream>>>(x, Wqt, Wkt, Wvt, Qf, Kf, Vf);
  attn_kernel<<<dim3(1024, 1, 1), 128, 0, stream>>>(Qf, Kf, Vf);
  outproj_kernel<<<dim3(256, 1, 1), 256, 0, stream>>>(Qf, Wot, bo, out);
}

// Round 9
// 136.202 us; speedup vs baseline: 1.8146x; 1.0758x over previous
//
#include <hip/hip_runtime.h>

typedef __bf16 bf16;
typedef __bf16 bf16x4 __attribute__((ext_vector_type(4)));
typedef __bf16 bf16x8 __attribute__((ext_vector_type(8)));
typedef float f32x4 __attribute__((ext_vector_type(4)));
typedef float f32x16 __attribute__((ext_vector_type(16)));
typedef int i32x4 __attribute__((ext_vector_type(4)));

#define MFMA16(a, b, c) __builtin_amdgcn_mfma_f32_16x16x32_bf16((a), (b), (c), 0, 0, 0)
#define MFMA32(a, b, c) __builtin_amdgcn_mfma_f32_32x32x16_bf16((a), (b), (c), 0, 0, 0)

__device__ __forceinline__ int swz16(int r, int c) { return (c ^ (r & 15)); }

__device__ __forceinline__ int cvt_pk_bf16(float lo, float hi) {
  int r;
  asm("v_cvt_pk_bf16_f32 %0, %1, %2" : "=v"(r) : "v"(lo), "v"(hi));
  return r;
}

// ---- fused weight transposes: z=0..2 Wq/Wk/Wv (128x1024), z=3 Wo (1024x128) ----
__global__ __launch_bounds__(256) void trW_kernel(
    const float* __restrict__ Wq, const float* __restrict__ Wk,
    const float* __restrict__ Wv, const float* __restrict__ Wo,
    bf16* __restrict__ outbase) {
  __shared__ bf16 tile[32][33];
  const int z = blockIdx.z;
  const float* ib = (z == 0) ? Wq : (z == 1) ? Wk : (z == 2) ? Wv : Wo;
  bf16* ob = outbase + (size_t)z * 131072;
  const int R = (z < 3) ? 128 : 1024;
  const int C = (z < 3) ? 1024 : 128;
  int r0 = (z < 3) ? blockIdx.y * 32 : blockIdx.x * 32;
  int c0 = (z < 3) ? blockIdx.x * 32 : blockIdx.y * 32;
  int tx = threadIdx.x & 31, ty = threadIdx.x >> 5;
#pragma unroll
  for (int i = 0; i < 4; ++i) {
    int r = ty + i * 8;
    tile[r][tx] = (bf16)ib[(size_t)(r0 + r) * C + (c0 + tx)];
  }
  __syncthreads();
#pragma unroll
  for (int i = 0; i < 4; ++i) {
    int r = ty + i * 8;
    ob[(size_t)(c0 + r) * R + (r0 + tx)] = tile[tx][r];
  }
}

// -------- QKV projection -> fragment-major Q/K [blk32][sub16][hi][lane][8], V likewise
__global__ __launch_bounds__(256) void proj_gemm(
    const float* __restrict__ x, const bf16* __restrict__ Wqt,
    const bf16* __restrict__ Wkt, const bf16* __restrict__ Wvt,
    bf16* __restrict__ Qf, bf16* __restrict__ Kf, bf16* __restrict__ Vf) {
  __shared__ __align__(16) bf16 As[128 * 128];
  __shared__ __align__(16) bf16 Bs[128 * 128];
  const int mt = blockIdx.x;
  const int nt = blockIdx.y;
  const int matid = nt >> 3, h = nt & 7;
  const bf16* W = (matid == 0) ? Wqt : (matid == 1) ? Wkt : Wvt;
  const int tid = threadIdx.x;
  const bf16* sb = W + (size_t)h * 128 * 128;
#pragma unroll
  for (int i = 0; i < 8; ++i) {  // stage x tile, fp32 -> bf16
    int c = tid + i * 256;
    int r = c >> 4, cc = c & 15;
    const f32x4* p = (const f32x4*)(x + (size_t)(mt * 128 + r) * 128 + cc * 8);
    f32x4 a = p[0], b = p[1];
    bf16x8 o;
#pragma unroll
    for (int j = 0; j < 4; ++j) { o[j] = (bf16)a[j]; o[4 + j] = (bf16)b[j]; }
    *(bf16x8*)&As[r * 128 + swz16(r, cc) * 8] = o;
  }
#pragma unroll
  for (int i = 0; i < 8; ++i) {
    int c = tid + i * 256;
    int r = c >> 4, cc = c & 15;
    *(bf16x8*)&Bs[r * 128 + swz16(r, cc) * 8] = *(const bf16x8*)(sb + (size_t)r * 128 + cc * 8);
  }
  __syncthreads();
  const int wave = tid >> 6, lane = tid & 63;
  const int wr = (wave >> 1) * 64, wc = (wave & 1) * 64;
  const int lr = lane & 15, lkb = lane >> 4;
  const f32x4 FZ = {0.f, 0.f, 0.f, 0.f};
  f32x4 acc[4][4];
#pragma unroll
  for (int mf = 0; mf < 4; ++mf)
#pragma unroll
    for (int nf = 0; nf < 4; ++nf) acc[mf][nf] = FZ;
  const bool qk = (matid < 2);
#pragma unroll
  for (int ks = 0; ks < 4; ++ks) {
    bf16x8 a[4], b[4];
#pragma unroll
    for (int mf = 0; mf < 4; ++mf) {
      int r = wr + mf * 16 + lr;
      a[mf] = *(const bf16x8*)&As[r * 128 + swz16(r, ks * 4 + lkb) * 8];
    }
#pragma unroll
    for (int nf = 0; nf < 4; ++nf) {
      int r = wc + nf * 16 + lr;
      b[nf] = *(const bf16x8*)&Bs[r * 128 + swz16(r, ks * 4 + lkb) * 8];
    }
    if (qk) {  // transposed C: rows = d, cols = token
#pragma unroll
      for (int mf = 0; mf < 4; ++mf)
#pragma unroll
        for (int nf = 0; nf < 4; ++nf) acc[mf][nf] = MFMA16(b[nf], a[mf], acc[mf][nf]);
    } else {
#pragma unroll
      for (int mf = 0; mf < 4; ++mf)
#pragma unroll
        for (int nf = 0; nf < 4; ++nf) acc[mf][nf] = MFMA16(a[mf], b[nf], acc[mf][nf]);
    }
  }
  const int rb = lkb * 4;
  if (qk) {  // Q/K fragment-major: lane holds token m, 4 consecutive d
    bf16* Out = (matid == 0) ? Qf : Kf;
#pragma unroll
    for (int mf = 0; mf < 4; ++mf)
#pragma unroll
      for (int nf = 0; nf < 4; ++nf) {
        int m = mt * 128 + wr + mf * 16 + lr;
        int d0 = wc + nf * 16 + rb;
        int bb = m >> 11, t = m & 2047;
        bf16x4 vv;
#pragma unroll
        for (int r = 0; r < 4; ++r) vv[r] = (bf16)acc[mf][nf][r];
        size_t e = (size_t)(bb * 8 + h) * 262144
                 + (size_t)(((t >> 5) * 8 + (d0 >> 4)) * 512 + ((d0 >> 3) & 1) * 256
                            + (t & 31) * 8 + (d0 & 7));
        *(bf16x4*)(Out + e) = vv;
      }
  } else {  // V fragment-major: lane holds dim d, 4 consecutive tokens
#pragma unroll
    for (int mf = 0; mf < 4; ++mf)
#pragma unroll
      for (int nf = 0; nf < 4; ++nf) {
        int d = wc + nf * 16 + lr;
        int m0 = mt * 128 + wr + mf * 16 + rb;
        int bb = m0 >> 11, t0 = m0 & 2047;
        bf16x4 vv;
#pragma unroll
        for (int r = 0; r < 4; ++r) vv[r] = (bf16)acc[mf][nf][r];
        size_t e = (size_t)(bb * 8 + h) * 262144
                 + (size_t)((d >> 5) * 65536 + (t0 >> 4) * 512 + ((t0 >> 3) & 1) * 256
                            + (d & 31) * 8 + (t0 & 7));
        *(bf16x4*)(Vf + e) = vv;
      }
  }
}

// ---- causal flash attention: 512 blocks x 4 waves; complementary q-tile pair,
// kv-split x4 per tile (uniform ~8-9 passes/wave), LDS merge tree, V-issue-early ----
__global__ __launch_bounds__(256) void attn_kernel(
    bf16* __restrict__ Qf, const bf16* __restrict__ Kf, const bf16* __restrict__ Vf) {
  __shared__ float Om0[128 * 32];
  __shared__ float Om1[128 * 32];
  __shared__ float L0m[32], L0l[32], L1m[32], L1l[32];
  const int bid = blockIdx.x;
  const int bh = bid & 15;          // bid&7 -> XCD; 2 heads per XCD (K/V L2-resident)
  const int pr = bid >> 4;          // 0..31: q-tile pair (pr, 63-pr)
  const int tid = threadIdx.x;
  const int w = tid >> 6, lane = tid & 63;
  const int lq = lane & 31, hi = lane >> 5;
  const int lo = hi * 256 + lq * 8;
  const bf16* Qh = Qf + (size_t)bh * 262144;
  const bf16* Kh = Kf + (size_t)bh * 262144;
  const bf16* Vh = Vf + (size_t)bh * 262144;
  const float SCL = 0.12751744f;    // log2(e)/sqrt(128)

  for (int ph = 0; ph < 2; ++ph) {
    const int qt = ph ? (63 - pr) : pr;
    const int nT = (qt >> 1) + 1;
    const int base = nT >> 2, rem = nT & 3;
    const int we = ph ? (3 - w) : w;     // rotate extra-tile waves across phases
    const int cnt = base + (we < rem ? 1 : 0);
    const int tb = we * base + (we < rem ? we : rem);

    bf16x8 qf[8];
#pragma unroll
    for (int ks = 0; ks < 8; ++ks)
      qf[ks] = *(const bf16x8*)(Qh + qt * 4096 + ks * 512 + lo);

    float mrun = -__builtin_inff(), lrun = 0.f;
    f32x16 O[4];
#pragma unroll
    for (int dt = 0; dt < 4; ++dt)
#pragma unroll
      for (int r = 0; r < 16; ++r) O[dt][r] = 0.f;

    for (int it = 0; it < cnt; ++it) {
      const int kvt = tb + it;
      const int kv0 = kvt * 64;
      // ---- K fragments direct from L2 ----
      const bf16* kbase = Kh + kvt * 8192 + lo;
      bf16x8 ka[8], kb[8];
#pragma unroll
      for (int i = 0; i < 8; ++i) ka[i] = *(const bf16x8*)(kbase + i * 512);
#pragma unroll
      for (int i = 0; i < 8; ++i) kb[i] = *(const bf16x8*)(kbase + 4096 + i * 512);
      // ---- QK^T swapped: p[row=kv, col=q] ----
      f32x16 p0, p1;
#pragma unroll
      for (int r = 0; r < 16; ++r) { p0[r] = 0.f; p1[r] = 0.f; }
      __builtin_amdgcn_s_setprio(1);
#pragma unroll
      for (int ks = 0; ks < 8; ++ks) p0 = MFMA32(ka[ks], qf[ks], p0);
#pragma unroll
      for (int ks = 0; ks < 8; ++ks) p1 = MFMA32(kb[ks], qf[ks], p1);
      __builtin_amdgcn_s_setprio(0);
      // ---- V loads issued NOW: latency hides under softmax ----
      const bf16* vbase = Vh + kvt * 2048 + lo;
      bf16x8 va[16];
#pragma unroll
      for (int i = 0; i < 16; ++i)
        va[i] = *(const bf16x8*)(vbase + (i >> 2) * 65536 + (i & 3) * 512);
      // ---- causal mask (diagonal tile only) ----
      if (kvt == (qt >> 1)) {
        const int qg = qt * 32 + lq;
#pragma unroll
        for (int r = 0; r < 16; ++r) {
          int kvr = kv0 + (r & 3) + 8 * (r >> 2) + 4 * hi;
          if (kvr > qg) p0[r] = -__builtin_inff();
          if (kvr + 32 > qg) p1[r] = -__builtin_inff();
        }
      }
      // ---- online softmax (tree-reduced, defer-max) ----
      float m0 = fmaxf(p0[0], p1[0]);
      float m1_ = fmaxf(p0[1], p1[1]);
      float m2 = fmaxf(p0[2], p1[2]);
      float m3 = fmaxf(p0[3], p1[3]);
#pragma unroll
      for (int r = 4; r < 16; r += 4) {
        m0 = fmaxf(m0, fmaxf(p0[r], p1[r]));
        m1_ = fmaxf(m1_, fmaxf(p0[r + 1], p1[r + 1]));
        m2 = fmaxf(m2, fmaxf(p0[r + 2], p1[r + 2]));
        m3 = fmaxf(m3, fmaxf(p0[r + 3], p1[r + 3]));
      }
      float pm = fmaxf(fmaxf(m0, m1_), fmaxf(m2, m3));
      pm = fmaxf(pm, __shfl_xor(pm, 32, 64));
      float pmS = pm * SCL;
      if (!__all(pmS <= mrun + 8.f)) {
        float mnew = fmaxf(mrun, pmS);
        float alpha = exp2f(mrun - mnew);
        mrun = mnew;
        lrun *= alpha;
#pragma unroll
        for (int dt = 0; dt < 4; ++dt)
#pragma unroll
          for (int r = 0; r < 16; ++r) O[dt][r] *= alpha;
      }
      float s0 = 0.f, s1 = 0.f, s2 = 0.f, s3 = 0.f;
#pragma unroll
      for (int r = 0; r < 16; r += 4) {
        float a0_ = exp2f(__builtin_fmaf(p0[r], SCL, -mrun));
        float a1_ = exp2f(__builtin_fmaf(p0[r + 1], SCL, -mrun));
        float a2_ = exp2f(__builtin_fmaf(p0[r + 2], SCL, -mrun));
        float a3_ = exp2f(__builtin_fmaf(p0[r + 3], SCL, -mrun));
        float b0_ = exp2f(__builtin_fmaf(p1[r], SCL, -mrun));
        float b1_ = exp2f(__builtin_fmaf(p1[r + 1], SCL, -mrun));
        float b2_ = exp2f(__builtin_fmaf(p1[r + 2], SCL, -mrun));
        float b3_ = exp2f(__builtin_fmaf(p1[r + 3], SCL, -mrun));
        p0[r] = a0_; p0[r + 1] = a1_; p0[r + 2] = a2_; p0[r + 3] = a3_;
        p1[r] = b0_; p1[r + 1] = b1_; p1[r + 2] = b2_; p1[r + 3] = b3_;
        s0 += a0_ + b0_; s1 += a1_ + b1_; s2 += a2_ + b2_; s3 += a3_ + b3_;
      }
      float ps = (s0 + s1) + (s2 + s3);
      ps += __shfl_xor(ps, 32, 64);
      lrun += ps;
      // ---- P -> bf16 B-frags in-register ----
      int wd[16];
#pragma unroll
      for (int i = 0; i < 8; ++i) wd[i] = cvt_pk_bf16(p0[2 * i], p0[2 * i + 1]);
#pragma unroll
      for (int i = 0; i < 8; ++i) wd[8 + i] = cvt_pk_bf16(p1[2 * i], p1[2 * i + 1]);
      bf16x8 pa[4];
#pragma unroll
      for (int t4 = 0; t4 < 4; ++t4) {
        int b0 = t4 * 4;
        int e0 = __shfl_xor(wd[b0 + 0], 32, 64);
        int e1 = __shfl_xor(wd[b0 + 1], 32, 64);
        int e2 = __shfl_xor(wd[b0 + 2], 32, 64);
        int e3 = __shfl_xor(wd[b0 + 3], 32, 64);
        i32x4 f;
        f[0] = hi ? e2 : wd[b0 + 0];
        f[1] = hi ? e3 : wd[b0 + 1];
        f[2] = hi ? wd[b0 + 2] : e0;
        f[3] = hi ? wd[b0 + 3] : e1;
        pa[t4] = __builtin_bit_cast(bf16x8, f);
      }
      // ---- O^T += V^T @ P^T ----
      __builtin_amdgcn_s_setprio(1);
#pragma unroll
      for (int dt = 0; dt < 4; ++dt) {
        O[dt] = MFMA32(va[dt * 4 + 0], pa[0], O[dt]);
        O[dt] = MFMA32(va[dt * 4 + 1], pa[1], O[dt]);
        O[dt] = MFMA32(va[dt * 4 + 2], pa[2], O[dt]);
        O[dt] = MFMA32(va[dt * 4 + 3], pa[3], O[dt]);
      }
      __builtin_amdgcn_s_setprio(0);
    }

    // ---- 4-way merge tree via LDS ----
    auto STORE = [&](float* Om, float* Lm, float* Ll) {
#pragma unroll
      for (int dt = 0; dt < 4; ++dt)
#pragma unroll
        for (int r = 0; r < 16; ++r)
          Om[(dt * 32 + (r & 3) + 8 * (r >> 2) + 4 * hi) * 32 + lq] = O[dt][r];
      if (!hi) { Lm[lq] = mrun; Ll[lq] = lrun; }
    };
    auto MERGE = [&](const float* Om, const float* Lm, const float* Ll) {
      float m1 = Lm[lq], l1 = Ll[lq];
      float mF = fmaxf(mrun, m1);
      float a0 = (mrun < -3.0e38f) ? 0.f : exp2f(mrun - mF);
      float a1 = (m1 < -3.0e38f) ? 0.f : exp2f(m1 - mF);
      lrun = lrun * a0 + l1 * a1;
#pragma unroll
      for (int dt = 0; dt < 4; ++dt)
#pragma unroll
        for (int r = 0; r < 16; ++r)
          O[dt][r] = O[dt][r] * a0 +
                     Om[(dt * 32 + (r & 3) + 8 * (r >> 2) + 4 * hi) * 32 + lq] * a1;
      mrun = mF;
    };

    __syncthreads();
    if (w == 1) STORE(Om0, L0m, L0l);
    if (w == 3) STORE(Om1, L1m, L1l);
    __syncthreads();
    if (w == 0) MERGE(Om0, L0m, L0l);
    if (w == 2) MERGE(Om1, L1m, L1l);
    __syncthreads();
    if (w == 2) STORE(Om0, L0m, L0l);
    __syncthreads();
    if (w == 0) {
      MERGE(Om0, L0m, L0l);
      float inv = 1.f / lrun;
      bf16* qw = Qf + (size_t)bh * 262144 + qt * 4096 + lq * 8 + 4 * hi;
#pragma unroll
      for (int dt = 0; dt < 4; ++dt) {
#pragma unroll
        for (int rq = 0; rq < 4; ++rq) {
          bf16x4 vv;
#pragma unroll
          for (int jj = 0; jj < 4; ++jj) {
            int r = rq * 4 + jj;
            vv[jj] = (bf16)(O[dt][r] * inv);
          }
          *(bf16x4*)(qw + (dt * 2 + (rq >> 1)) * 512 + (rq & 1) * 256) = vv;
        }
      }
    }
    __syncthreads();  // buffers free before next phase
  }
}

// ------- output projection: AO (fragment-major) @ Wot [128][1024] + bo -> fp32 out --
__global__ __launch_bounds__(256) void outproj_kernel(
    const bf16* __restrict__ AO, const bf16* __restrict__ Wot,
    const float* __restrict__ bo, float* __restrict__ out) {
  __shared__ __align__(16) bf16 As[16 * 128];
  __shared__ __align__(16) bf16 Bs[128 * 128];
  const f32x4 FZ = {0.f, 0.f, 0.f, 0.f};
  const int mt = blockIdx.x;  // 256 tiles of 16 rows
  const int tid = threadIdx.x, wave = tid >> 6, lane = tid & 63;
  const int lr = lane & 15, lkb = lane >> 4, rb = lkb * 4;
  const int wc = wave * 32;
  f32x4 acc[2];
  acc[0] = FZ; acc[1] = FZ;
  for (int kt = 0; kt < 8; ++kt) {  // kt == head index
    __syncthreads();
    {
      int r = tid >> 4, cc = tid & 15;
      int m = mt * 16 + r, bb = m >> 11, t = m & 2047;
      const bf16* src = AO + (size_t)(bb * 8 + kt) * 262144
          + ((t >> 5) * 8 + (cc >> 1)) * 512 + (cc & 1) * 256 + (t & 31) * 8;
      *(bf16x8*)&As[r * 128 + swz16(r, cc) * 8] = *(const bf16x8*)src;
    }
#pragma unroll
    for (int i = 0; i < 8; ++i) {
      int c = tid + i * 256;
      int r = c >> 4, cc = c & 15;
      *(bf16x8*)&Bs[r * 128 + swz16(r, cc) * 8] =
          *(const bf16x8*)(Wot + (size_t)r * 1024 + kt * 128 + cc * 8);
    }
    __syncthreads();
#pragma unroll
    for (int ks = 0; ks < 4; ++ks) {
      bf16x8 a = *(const bf16x8*)&As[lr * 128 + swz16(lr, ks * 4 + lkb) * 8];
#pragma unroll
      for (int nf = 0; nf < 2; ++nf) {
        int r = wc + nf * 16 + lr;
        bf16x8 b = *(const bf16x8*)&Bs[r * 128 + swz16(r, ks * 4 + lkb) * 8];
        acc[nf] = MFMA16(a, b, acc[nf]);
      }
    }
  }
#pragma unroll
  for (int nf = 0; nf < 2; ++nf)
#pragma unroll
    for (int r = 0; r < 4; ++r) {
      int m = mt * 16 + rb + r;
      int n = wc + nf * 16 + lr;
      out[(size_t)m * 128 + n] = acc[nf][r] + bo[n];
    }
}

extern "C" void kernel_launch(void* const* d_in, const int* in_sizes, int n_in,
                              void* d_out, int out_size, void* d_ws, size_t ws_size,
                              hipStream_t stream) {
  (void)in_sizes; (void)n_in; (void)out_size; (void)ws_size;
  const float* x  = (const float*)d_in[0];
  const float* Wq = (const float*)d_in[1];
  const float* Wk = (const float*)d_in[2];
  const float* Wv = (const float*)d_in[3];
  const float* Wo = (const float*)d_in[4];
  const float* bo = (const float*)d_in[5];
  float* out = (float*)d_out;

  bf16* ws  = (bf16*)d_ws;
  bf16* Wqt = ws;                 // [3][1024][128]
  bf16* Wkt = Wqt + 131072;
  bf16* Wvt = Wkt + 131072;
  bf16* Wot = Wvt + 131072;       // [128][1024]
  bf16* Qf  = Wot + 131072;       // [16] fragment-major Q; attn output in-place
  bf16* Kf  = Qf + 4194304;
  bf16* Vf  = Kf + 4194304;

  trW_kernel<<<dim3(32, 4, 4), 256, 0, stream>>>(Wq, Wk, Wv, Wo, Wqt);
  proj_gemm<<<dim3(32, 24, 1), 256, 0, stream>>>(x, Wqt, Wkt, Wvt, Qf, Kf, Vf);
  attn_kernel<<<dim3(512, 1, 1), 256, 0, stream>>>(Qf, Kf, Vf);
  outproj_kernel<<<dim3(256, 1, 1), 256, 0, stream>>>(Qf, Wot, bo, out);
}